// Round 1
// baseline (3930.366 us; speedup 1.0000x reference)
//
#include <hip/hip_runtime.h>
#include <hip/hip_bf16.h>
#include <cstdint>

#define NODES 50000
#define EDGES 400000
#define FIN   988
#define FH    256
#define FC    47

// ---------------- degree ----------------
__global__ void k_deg_count(const int* __restrict__ dst, float* __restrict__ deg, int nE) {
    int i = blockIdx.x * blockDim.x + threadIdx.x;
    if (i < nE) atomicAdd(&deg[dst[i]], 1.0f);
}

__global__ void k_deg_recip(float* __restrict__ deg, int n) {
    int i = blockIdx.x * blockDim.x + threadIdx.x;
    if (i < n) deg[i] = 1.0f / fmaxf(deg[i], 1.0f);
}

// ---------------- fp32 tiled GEMM: C[M,N] = A[M,K] @ B[K,N] (row-major, guarded) ----------------
#define BM 64
#define BN 64
#define BK 16

__global__ __launch_bounds__(256) void k_gemm(const float* __restrict__ A,
                                              const float* __restrict__ B,
                                              float* __restrict__ C,
                                              int M, int N, int K) {
    __shared__ float As[BK][BM];   // transposed A tile: As[k][m]
    __shared__ float Bs[BK][BN];
    const int bm = blockIdx.y * BM;
    const int bn = blockIdx.x * BN;
    const int t  = threadIdx.x;
    const int tr4 = (t >> 4) << 2;   // 0..60, row offset of 4x4 microtile
    const int tc4 = (t & 15) << 2;   // 0..60, col offset
    float acc[4][4] = {{0.f,0.f,0.f,0.f},{0.f,0.f,0.f,0.f},{0.f,0.f,0.f,0.f},{0.f,0.f,0.f,0.f}};

    for (int k0 = 0; k0 < K; k0 += BK) {
        {   // A tile: thread t -> row r=t>>2, cols c..c+3 with c=(t&3)*4
            const int r = t >> 2;
            const int c = (t & 3) << 2;
            const int row = bm + r;
            float v0 = 0.f, v1 = 0.f, v2 = 0.f, v3 = 0.f;
            if (row < M) {
                const float* ap = A + (size_t)row * K + k0 + c;
                if (k0 + c + 3 < K) {
                    float4 v = *(const float4*)ap;
                    v0 = v.x; v1 = v.y; v2 = v.z; v3 = v.w;
                } else {
                    if (k0 + c + 0 < K) v0 = ap[0];
                    if (k0 + c + 1 < K) v1 = ap[1];
                    if (k0 + c + 2 < K) v2 = ap[2];
                    if (k0 + c + 3 < K) v3 = ap[3];
                }
            }
            As[c + 0][r] = v0; As[c + 1][r] = v1; As[c + 2][r] = v2; As[c + 3][r] = v3;
        }
        {   // B tile: thread t -> row kk=t>>4, cols c..c+3 with c=(t&15)*4
            const int kk = t >> 4;
            const int c  = (t & 15) << 2;
            float4 v = make_float4(0.f, 0.f, 0.f, 0.f);
            if (k0 + kk < K) {
                const float* bp = B + (size_t)(k0 + kk) * N + bn + c;
                if (bn + c + 3 < N) {
                    v = *(const float4*)bp;
                } else {
                    if (bn + c + 0 < N) v.x = bp[0];
                    if (bn + c + 1 < N) v.y = bp[1];
                    if (bn + c + 2 < N) v.z = bp[2];
                    if (bn + c + 3 < N) v.w = bp[3];
                }
            }
            *(float4*)&Bs[kk][c] = v;
        }
        __syncthreads();
#pragma unroll
        for (int k = 0; k < BK; ++k) {
            float4 a = *(const float4*)&As[k][tr4];
            float4 b = *(const float4*)&Bs[k][tc4];
            acc[0][0] += a.x*b.x; acc[0][1] += a.x*b.y; acc[0][2] += a.x*b.z; acc[0][3] += a.x*b.w;
            acc[1][0] += a.y*b.x; acc[1][1] += a.y*b.y; acc[1][2] += a.y*b.z; acc[1][3] += a.y*b.w;
            acc[2][0] += a.z*b.x; acc[2][1] += a.z*b.y; acc[2][2] += a.z*b.z; acc[2][3] += a.z*b.w;
            acc[3][0] += a.w*b.x; acc[3][1] += a.w*b.y; acc[3][2] += a.w*b.z; acc[3][3] += a.w*b.w;
        }
        __syncthreads();
    }

#pragma unroll
    for (int i = 0; i < 4; ++i) {
        const int row = bm + tr4 + i;
        if (row >= M) continue;
#pragma unroll
        for (int j = 0; j < 4; ++j) {
            const int col = bn + tc4 + j;
            if (col < N) C[(size_t)row * N + col] = acc[i][j];
        }
    }
}

// ---------------- edge scatter (segment_sum) ----------------
// F = 256: one 64-lane wave per edge, float4 per lane.
__global__ void k_scatter256(const float* __restrict__ hw, const int* __restrict__ src,
                             const int* __restrict__ dst, float* __restrict__ agg, int nE) {
    int gid = blockIdx.x * blockDim.x + threadIdx.x;
    int e = gid >> 6;
    if (e >= nE) return;
    int l = (gid & 63) << 2;
    int s = src[e], d = dst[e];
    const float4 v = *(const float4*)&hw[(size_t)s * FH + l];
    float* o = &agg[(size_t)d * FH + l];
    atomicAdd(o + 0, v.x);
    atomicAdd(o + 1, v.y);
    atomicAdd(o + 2, v.z);
    atomicAdd(o + 3, v.w);
}

// F = 47: 64 threads per edge, scalar, lanes >= 47 idle.
__global__ void k_scatter47(const float* __restrict__ hw, const int* __restrict__ src,
                            const int* __restrict__ dst, float* __restrict__ agg, int nE) {
    int gid = blockIdx.x * blockDim.x + threadIdx.x;
    int e = gid >> 6;
    if (e >= nE) return;
    int l = gid & 63;
    if (l >= FC) return;
    int s = src[e], d = dst[e];
    atomicAdd(&agg[(size_t)d * FC + l], hw[(size_t)s * FC + l]);
}

// ---------------- combine: out = [relu](hself + agg*dinv[row] + bias) ----------------
__global__ void k_combine(const float* __restrict__ hself, const float* __restrict__ agg,
                          const float* __restrict__ dinv, const float* __restrict__ bias,
                          float* __restrict__ out, int N, int do_relu) {
    int i = blockIdx.y;
    int j = blockIdx.x * blockDim.x + threadIdx.x;
    if (j >= N) return;
    size_t idx = (size_t)i * N + j;
    float v = hself[idx] + agg[idx] * dinv[i] + bias[j];
    if (do_relu) v = fmaxf(v, 0.f);
    out[idx] = v;
}

extern "C" void kernel_launch(void* const* d_in, const int* in_sizes, int n_in,
                              void* d_out, int out_size, void* d_ws, size_t ws_size,
                              hipStream_t stream) {
    const float* x       = (const float*)d_in[0];
    const int*   src     = (const int*)d_in[1];
    const int*   dst     = (const int*)d_in[2];
    const float* Wself0  = (const float*)d_in[3];
    const float* Wneigh0 = (const float*)d_in[4];
    const float* b0      = (const float*)d_in[5];
    const float* Wself1  = (const float*)d_in[6];
    const float* Wneigh1 = (const float*)d_in[7];
    const float* b1      = (const float*)d_in[8];
    const float* Wself2  = (const float*)d_in[9];
    const float* Wneigh2 = (const float*)d_in[10];
    const float* b2      = (const float*)d_in[11];
    float* out = (float*)d_out;

    const size_t SZ = (size_t)NODES * FH * sizeof(float);   // 51.2 MB
    float* bufA = (float*)((char*)d_ws + 0 * SZ);
    float* bufB = (float*)((char*)d_ws + 1 * SZ);
    float* bufC = (float*)((char*)d_ws + 2 * SZ);
    float* dinv = (float*)((char*)d_ws + 3 * SZ);

    dim3 blk(256);

    // degree -> reciprocal (shared across layers)
    hipMemsetAsync(dinv, 0, NODES * sizeof(float), stream);
    k_deg_count<<<(EDGES + 255) / 256, blk, 0, stream>>>(dst, dinv, EDGES);
    k_deg_recip<<<(NODES + 255) / 256, blk, 0, stream>>>(dinv, NODES);

    const int scat_blocks = (int)(((size_t)EDGES * 64 + 255) / 256);

    // ---- Layer 0: x(50000x988) ----
    dim3 gH((FH + BN - 1) / BN, (NODES + BM - 1) / BM);
    k_gemm<<<gH, blk, 0, stream>>>(x, Wself0,  bufA, NODES, FH, FIN);
    k_gemm<<<gH, blk, 0, stream>>>(x, Wneigh0, bufB, NODES, FH, FIN);
    hipMemsetAsync(bufC, 0, SZ, stream);
    k_scatter256<<<scat_blocks, blk, 0, stream>>>(bufB, src, dst, bufC, EDGES);
    k_combine<<<dim3(1, NODES), blk, 0, stream>>>(bufA, bufC, dinv, b0, bufA, FH, 1);

    // ---- Layer 1: h1 = bufA (50000x256) ----
    k_gemm<<<gH, blk, 0, stream>>>(bufA, Wself1,  bufB, NODES, FH, FH);
    k_gemm<<<gH, blk, 0, stream>>>(bufA, Wneigh1, bufC, NODES, FH, FH);
    hipMemsetAsync(bufA, 0, SZ, stream);
    k_scatter256<<<scat_blocks, blk, 0, stream>>>(bufC, src, dst, bufA, EDGES);
    k_combine<<<dim3(1, NODES), blk, 0, stream>>>(bufB, bufA, dinv, b1, bufB, FH, 1);

    // ---- Layer 2: h2 = bufB (50000x256) -> out 50000x47 ----
    dim3 gC((FC + BN - 1) / BN, (NODES + BM - 1) / BM);
    k_gemm<<<gC, blk, 0, stream>>>(bufB, Wself2,  bufA, NODES, FC, FH);
    k_gemm<<<gC, blk, 0, stream>>>(bufB, Wneigh2, bufC, NODES, FC, FH);
    hipMemsetAsync(bufB, 0, (size_t)NODES * FC * sizeof(float), stream);
    k_scatter47<<<scat_blocks, blk, 0, stream>>>(bufC, src, dst, bufB, EDGES);
    k_combine<<<dim3(1, NODES), blk, 0, stream>>>(bufA, bufB, dinv, b2, out, FC, 0);
}

// Round 2
// 1381.500 us; speedup vs baseline: 2.8450x; 2.8450x over previous
//
#include <hip/hip_runtime.h>
#include <hip/hip_bf16.h>
#include <cstdint>

#define NODES 50000
#define EDGES 400000
#define FIN   988
#define FH    256
#define FC    47

// ---------------- CSR build ----------------
__global__ void k_deg_count(const int* __restrict__ dst, int* __restrict__ deg, int nE) {
    int i = blockIdx.x * blockDim.x + threadIdx.x;
    if (i < nE) atomicAdd(&deg[dst[i]], 1);
}

// single-block exclusive scan of deg[n] -> rowptr[n+1]; also (re)init cursor=rowptr[i].
// deg and cursor may alias.
__global__ __launch_bounds__(1024) void k_scan(const int* __restrict__ deg,
                                               int* __restrict__ rowptr,
                                               int* __restrict__ cursor, int n) {
    __shared__ int sums[1024];
    const int t = threadIdx.x;
    const int chunk = (n + 1023) / 1024;
    const int b = t * chunk;
    const int e = min(b + chunk, n);
    int s = 0;
    for (int i = b; i < e; ++i) s += deg[i];
    sums[t] = s;
    __syncthreads();
    for (int off = 1; off < 1024; off <<= 1) {
        int v = 0;
        if (t >= off) v = sums[t - off];
        __syncthreads();
        if (t >= off) sums[t] += v;
        __syncthreads();
    }
    int excl = (t == 0) ? 0 : sums[t - 1];
    for (int i = b; i < e; ++i) {
        int d = deg[i];          // read BEFORE clobbering (deg may alias cursor)
        rowptr[i] = excl;
        cursor[i] = excl;
        excl += d;
    }
    if (t == 1023) rowptr[n] = sums[1023];
}

__global__ void k_fill(const int* __restrict__ src, const int* __restrict__ dst,
                       int* __restrict__ cursor, int* __restrict__ eidx, int nE) {
    int i = blockIdx.x * blockDim.x + threadIdx.x;
    if (i < nE) {
        int d = dst[i];
        int p = atomicAdd(&cursor[d], 1);
        eidx[p] = src[i];
    }
}

// ---------------- fp32 tiled GEMM: C[M,N] = A[M,K] @ B[K,N] (row-major, guarded) ----------------
#define BM 64
#define BN 64
#define BK 16

__global__ __launch_bounds__(256) void k_gemm(const float* __restrict__ A,
                                              const float* __restrict__ B,
                                              float* __restrict__ C,
                                              int M, int N, int K) {
    __shared__ float As[BK][BM];   // transposed A tile: As[k][m]
    __shared__ float Bs[BK][BN];
    const int bm = blockIdx.y * BM;
    const int bn = blockIdx.x * BN;
    const int t  = threadIdx.x;
    const int tr4 = (t >> 4) << 2;
    const int tc4 = (t & 15) << 2;
    float acc[4][4] = {{0.f,0.f,0.f,0.f},{0.f,0.f,0.f,0.f},{0.f,0.f,0.f,0.f},{0.f,0.f,0.f,0.f}};

    for (int k0 = 0; k0 < K; k0 += BK) {
        {
            const int r = t >> 2;
            const int c = (t & 3) << 2;
            const int row = bm + r;
            float v0 = 0.f, v1 = 0.f, v2 = 0.f, v3 = 0.f;
            if (row < M) {
                const float* ap = A + (size_t)row * K + k0 + c;
                if (k0 + c + 3 < K) {
                    float4 v = *(const float4*)ap;
                    v0 = v.x; v1 = v.y; v2 = v.z; v3 = v.w;
                } else {
                    if (k0 + c + 0 < K) v0 = ap[0];
                    if (k0 + c + 1 < K) v1 = ap[1];
                    if (k0 + c + 2 < K) v2 = ap[2];
                    if (k0 + c + 3 < K) v3 = ap[3];
                }
            }
            As[c + 0][r] = v0; As[c + 1][r] = v1; As[c + 2][r] = v2; As[c + 3][r] = v3;
        }
        {
            const int kk = t >> 4;
            const int c  = (t & 15) << 2;
            float4 v = make_float4(0.f, 0.f, 0.f, 0.f);
            if (k0 + kk < K) {
                const float* bp = B + (size_t)(k0 + kk) * N + bn + c;
                if (bn + c + 3 < N) {
                    v = *(const float4*)bp;
                } else {
                    if (bn + c + 0 < N) v.x = bp[0];
                    if (bn + c + 1 < N) v.y = bp[1];
                    if (bn + c + 2 < N) v.z = bp[2];
                    if (bn + c + 3 < N) v.w = bp[3];
                }
            }
            *(float4*)&Bs[kk][c] = v;
        }
        __syncthreads();
#pragma unroll
        for (int k = 0; k < BK; ++k) {
            float4 a = *(const float4*)&As[k][tr4];
            float4 b = *(const float4*)&Bs[k][tc4];
            acc[0][0] += a.x*b.x; acc[0][1] += a.x*b.y; acc[0][2] += a.x*b.z; acc[0][3] += a.x*b.w;
            acc[1][0] += a.y*b.x; acc[1][1] += a.y*b.y; acc[1][2] += a.y*b.z; acc[1][3] += a.y*b.w;
            acc[2][0] += a.z*b.x; acc[2][1] += a.z*b.y; acc[2][2] += a.z*b.z; acc[2][3] += a.z*b.w;
            acc[3][0] += a.w*b.x; acc[3][1] += a.w*b.y; acc[3][2] += a.w*b.z; acc[3][3] += a.w*b.w;
        }
        __syncthreads();
    }

#pragma unroll
    for (int i = 0; i < 4; ++i) {
        const int row = bm + tr4 + i;
        if (row >= M) continue;
#pragma unroll
        for (int j = 0; j < 4; ++j) {
            const int col = bn + tc4 + j;
            if (col < N) C[(size_t)row * N + col] = acc[i][j];
        }
    }
}

// ---------------- fused gather-aggregate + combine, F=256 ----------------
// one 64-lane wave per node; float4 per lane. inout holds hself on entry, h_next on exit.
__global__ void k_gac256(const float* __restrict__ hw, const int* __restrict__ rowptr,
                         const int* __restrict__ eidx, const float* __restrict__ bias,
                         float* __restrict__ inout, int do_relu) {
    int gid = blockIdx.x * blockDim.x + threadIdx.x;
    int node = gid >> 6;
    if (node >= NODES) return;
    const int l4 = (gid & 63) << 2;
    const int beg = rowptr[node];
    const int end = rowptr[node + 1];
    float ax = 0.f, ay = 0.f, az = 0.f, aw = 0.f;
    for (int e = beg; e < end; ++e) {
        const int s = eidx[e];
        const float4 v = *(const float4*)&hw[(size_t)s * FH + l4];
        ax += v.x; ay += v.y; az += v.z; aw += v.w;
    }
    const float inv = 1.f / (float)max(end - beg, 1);
    float* p = &inout[(size_t)node * FH + l4];
    const float4 hs = *(const float4*)p;
    const float4 b  = *(const float4*)&bias[l4];
    float4 o;
    o.x = hs.x + ax * inv + b.x;
    o.y = hs.y + ay * inv + b.y;
    o.z = hs.z + az * inv + b.z;
    o.w = hs.w + aw * inv + b.w;
    if (do_relu) {
        o.x = fmaxf(o.x, 0.f); o.y = fmaxf(o.y, 0.f);
        o.z = fmaxf(o.z, 0.f); o.w = fmaxf(o.w, 0.f);
    }
    *(float4*)p = o;
}

// ---------------- fused gather-aggregate + combine, F=47 (final layer) ----------------
__global__ void k_gac47(const float* __restrict__ hw, const int* __restrict__ rowptr,
                        const int* __restrict__ eidx, const float* __restrict__ bias,
                        const float* __restrict__ hself, float* __restrict__ out) {
    int gid = blockIdx.x * blockDim.x + threadIdx.x;
    int node = gid >> 6;
    if (node >= NODES) return;
    const int l = gid & 63;
    if (l >= FC) return;
    const int beg = rowptr[node];
    const int end = rowptr[node + 1];
    float acc = 0.f;
    for (int e = beg; e < end; ++e) {
        const int s = eidx[e];
        acc += hw[(size_t)s * FC + l];
    }
    const float inv = 1.f / (float)max(end - beg, 1);
    out[(size_t)node * FC + l] = hself[(size_t)node * FC + l] + acc * inv + bias[l];
}

extern "C" void kernel_launch(void* const* d_in, const int* in_sizes, int n_in,
                              void* d_out, int out_size, void* d_ws, size_t ws_size,
                              hipStream_t stream) {
    const float* x       = (const float*)d_in[0];
    const int*   src     = (const int*)d_in[1];
    const int*   dst     = (const int*)d_in[2];
    const float* Wself0  = (const float*)d_in[3];
    const float* Wneigh0 = (const float*)d_in[4];
    const float* b0      = (const float*)d_in[5];
    const float* Wself1  = (const float*)d_in[6];
    const float* Wneigh1 = (const float*)d_in[7];
    const float* b1      = (const float*)d_in[8];
    const float* Wself2  = (const float*)d_in[9];
    const float* Wneigh2 = (const float*)d_in[10];
    const float* b2      = (const float*)d_in[11];
    float* out = (float*)d_out;

    const size_t SZ = (size_t)NODES * FH * sizeof(float);   // 51.2 MB
    float* bufA = (float*)((char*)d_ws + 0 * SZ);
    float* bufB = (float*)((char*)d_ws + 1 * SZ);
    float* bufC = (float*)((char*)d_ws + 2 * SZ);
    int*   rowptr = (int*)((char*)d_ws + 3 * SZ);     // NODES+1
    int*   cursor = rowptr + (NODES + 1);             // NODES (also deg)
    int*   eidx   = cursor + NODES;                   // EDGES

    dim3 blk(256);

    // ---- CSR build (deg -> rowptr -> bucket fill) ----
    hipMemsetAsync(cursor, 0, NODES * sizeof(int), stream);
    k_deg_count<<<(EDGES + 255) / 256, blk, 0, stream>>>(dst, cursor, EDGES);
    k_scan<<<1, 1024, 0, stream>>>(cursor, rowptr, cursor, NODES);
    k_fill<<<(EDGES + 255) / 256, blk, 0, stream>>>(src, dst, cursor, eidx, EDGES);

    const int gat_blocks = (int)(((size_t)NODES * 64 + 255) / 256);

    // ---- Layer 0: x(50000x988) -> h1 = bufA ----
    dim3 gH((FH + BN - 1) / BN, (NODES + BM - 1) / BM);
    k_gemm<<<gH, blk, 0, stream>>>(x, Wself0,  bufA, NODES, FH, FIN);
    k_gemm<<<gH, blk, 0, stream>>>(x, Wneigh0, bufB, NODES, FH, FIN);
    k_gac256<<<gat_blocks, blk, 0, stream>>>(bufB, rowptr, eidx, b0, bufA, 1);

    // ---- Layer 1: h1 = bufA -> h2 = bufC ----
    k_gemm<<<gH, blk, 0, stream>>>(bufA, Wself1,  bufC, NODES, FH, FH);
    k_gemm<<<gH, blk, 0, stream>>>(bufA, Wneigh1, bufB, NODES, FH, FH);
    k_gac256<<<gat_blocks, blk, 0, stream>>>(bufB, rowptr, eidx, b1, bufC, 1);

    // ---- Layer 2: h2 = bufC -> out (50000x47) ----
    dim3 gC((FC + BN - 1) / BN, (NODES + BM - 1) / BM);
    k_gemm<<<gC, blk, 0, stream>>>(bufC, Wself2,  bufA, NODES, FC, FH);
    k_gemm<<<gC, blk, 0, stream>>>(bufC, Wneigh2, bufB, NODES, FC, FH);
    k_gac47<<<gat_blocks, blk, 0, stream>>>(bufB, rowptr, eidx, b2, bufA, out);
}

// Round 3
// 551.056 us; speedup vs baseline: 7.1324x; 2.5070x over previous
//
#include <hip/hip_runtime.h>
#include <hip/hip_bf16.h>
#include <cstdint>

#define NODES 50000
#define EDGES 400000
#define FIN   988
#define KP0   992      // FIN padded to multiple of 32
#define FH    256
#define FC    47

typedef __attribute__((ext_vector_type(8))) short short8;
typedef __attribute__((ext_vector_type(4))) float f32x4;

__device__ __forceinline__ ushort f2bf(float x) {      // RNE f32 -> bf16
    union { float f; uint32_t u; } v; v.f = x;
    uint32_t r = v.u + 0x7FFF + ((v.u >> 16) & 1);
    return (ushort)(r >> 16);
}
__device__ __forceinline__ float bf2f(ushort u) {
    union { uint32_t u; float f; } v; v.u = ((uint32_t)u) << 16;
    return v.f;
}

// ---------------- CSR build ----------------
__global__ void k_deg_count(const int* __restrict__ dst, int* __restrict__ deg, int nE) {
    int i = blockIdx.x * blockDim.x + threadIdx.x;
    if (i < nE) atomicAdd(&deg[dst[i]], 1);
}

__global__ __launch_bounds__(1024) void k_scan(const int* __restrict__ deg,
                                               int* __restrict__ rowptr,
                                               int* __restrict__ cursor, int n) {
    __shared__ int sums[1024];
    const int t = threadIdx.x;
    const int chunk = (n + 1023) / 1024;
    const int b = t * chunk;
    const int e = min(b + chunk, n);
    int s = 0;
    for (int i = b; i < e; ++i) s += deg[i];
    sums[t] = s;
    __syncthreads();
    for (int off = 1; off < 1024; off <<= 1) {
        int v = 0;
        if (t >= off) v = sums[t - off];
        __syncthreads();
        if (t >= off) sums[t] += v;
        __syncthreads();
    }
    int excl = (t == 0) ? 0 : sums[t - 1];
    for (int i = b; i < e; ++i) {
        int d = deg[i];
        rowptr[i] = excl;
        cursor[i] = excl;
        excl += d;
    }
    if (t == 1023) rowptr[n] = sums[1023];
}

__global__ void k_fill(const int* __restrict__ src, const int* __restrict__ dst,
                       int* __restrict__ cursor, int* __restrict__ eidx, int nE) {
    int i = blockIdx.x * blockDim.x + threadIdx.x;
    if (i < nE) {
        int d = dst[i];
        int p = atomicAdd(&cursor[d], 1);
        eidx[p] = src[i];
    }
}

// ---------------- weight transpose+convert: Wt[n][k] = W[k][n], bf16, zero-padded ----------------
__global__ void k_cvtw0(const float* __restrict__ Ws, const float* __restrict__ Wn,
                        ushort* __restrict__ Wt) {
    int gid = blockIdx.x * blockDim.x + threadIdx.x;
    if (gid >= 512 * KP0) return;
    int n = gid / KP0, k = gid - n * KP0;
    float v = 0.f;
    if (k < FIN) v = (n < FH) ? Ws[(size_t)k * FH + n] : Wn[(size_t)k * FH + (n - FH)];
    Wt[gid] = f2bf(v);
}

__global__ void k_cvtw1(const float* __restrict__ Ws, const float* __restrict__ Wn,
                        ushort* __restrict__ Wt) {
    int gid = blockIdx.x * blockDim.x + threadIdx.x;
    if (gid >= 512 * FH) return;
    int n = gid >> 8, k = gid & 255;
    float v = (n < FH) ? Ws[(size_t)k * FH + n] : Wn[(size_t)k * FH + (n - FH)];
    Wt[gid] = f2bf(v);
}

// Wt2: [128][256]; rows 0-46 = Wself2^T, rows 64-110 = Wneigh2^T, rest 0
__global__ void k_cvtw2(const float* __restrict__ Ws, const float* __restrict__ Wn,
                        ushort* __restrict__ Wt) {
    int gid = blockIdx.x * blockDim.x + threadIdx.x;
    if (gid >= 128 * FH) return;
    int n = gid >> 8, k = gid & 255;
    float v = 0.f;
    if (n < FC) v = Ws[(size_t)k * FC + n];
    else if (n >= 64 && n < 64 + FC) v = Wn[(size_t)k * FC + (n - 64)];
    Wt[gid] = f2bf(v);
}

// ---------------- bf16 MFMA GEMM: C[M][ldc](bf16) = A[M][lda] @ Bt[N][Kpad]^T ----------------
// 128x128 tile, BK=32, 4 waves (2x2), 4x4 16x16x32 fragments per wave.
// AF32: A is f32 (converted in-flight), else A is bf16 (ushort).
#define BMT 128
#define BKT 32

template<int AF32>
__global__ __launch_bounds__(256) void k_mm(const void* __restrict__ Ap,
                                            const ushort* __restrict__ Bt,
                                            ushort* __restrict__ C,
                                            const int M, const int lda,
                                            const int Ka, const int Kpad,
                                            const int ldc) {
    __shared__ ushort As[BMT * BKT];
    __shared__ ushort Bs[BMT * BKT];
    const int t = threadIdx.x;
    const int bm = blockIdx.y * BMT;
    const int bn = blockIdx.x * BMT;
    const int wid = t >> 6, lane = t & 63;
    const int wr = (wid >> 1) * 64, wc = (wid & 1) * 64;
    const int lr = lane & 15, g = lane >> 4;

    f32x4 acc[4][4] = {};

    const int sr = t >> 1;          // staging row 0..127
    const int kb = (t & 1) * 16;    // k-chunk offset within tile
    const int s0 = (t & 1) * 2;     // first 16B slot
    const int sw = (sr >> 1) & 3;   // swizzle key for this row

    for (int k0 = 0; k0 < Kpad; k0 += BKT) {
        const int kk = k0 + kb;
        ushort ua[16];
        if (AF32) {
            const float* A = (const float*)Ap;
            const int row = bm + sr;
            if (row < M && kk + 15 < Ka) {
                const float* p = A + (size_t)row * lda + kk;
                f32x4 v0 = *(const f32x4*)(p);
                f32x4 v1 = *(const f32x4*)(p + 4);
                f32x4 v2 = *(const f32x4*)(p + 8);
                f32x4 v3 = *(const f32x4*)(p + 12);
#pragma unroll
                for (int i = 0; i < 4; ++i) {
                    ua[i] = f2bf(v0[i]); ua[4 + i] = f2bf(v1[i]);
                    ua[8 + i] = f2bf(v2[i]); ua[12 + i] = f2bf(v3[i]);
                }
            } else {
#pragma unroll
                for (int i = 0; i < 16; ++i) {
                    float f = (row < M && kk + i < Ka) ? A[(size_t)row * lda + kk + i] : 0.f;
                    ua[i] = f2bf(f);
                }
            }
        } else {
            const ushort* A = (const ushort*)Ap;
            const int row = bm + sr;
            if (row < M) {
                const ushort* p = A + (size_t)row * lda + kk;
                *(short8*)&ua[0] = *(const short8*)p;
                *(short8*)&ua[8] = *(const short8*)(p + 8);
            } else {
#pragma unroll
                for (int i = 0; i < 16; ++i) ua[i] = 0;
            }
        }
        ushort ub[16];
        {
            const ushort* p = Bt + (size_t)(bn + sr) * Kpad + kk;
            *(short8*)&ub[0] = *(const short8*)p;
            *(short8*)&ub[8] = *(const short8*)(p + 8);
        }
        __syncthreads();   // previous iter's frag reads done before overwrite
        *(short8*)&As[sr * BKT + ((s0 ^ sw) * 8)]       = *(short8*)&ua[0];
        *(short8*)&As[sr * BKT + (((s0 + 1) ^ sw) * 8)] = *(short8*)&ua[8];
        *(short8*)&Bs[sr * BKT + ((s0 ^ sw) * 8)]       = *(short8*)&ub[0];
        *(short8*)&Bs[sr * BKT + (((s0 + 1) ^ sw) * 8)] = *(short8*)&ub[8];
        __syncthreads();

        short8 af[4], bfr[4];
#pragma unroll
        for (int m = 0; m < 4; ++m) {
            const int row = wr + m * 16 + lr;
            af[m] = *(const short8*)&As[row * BKT + ((g ^ ((row >> 1) & 3)) * 8)];
        }
#pragma unroll
        for (int n = 0; n < 4; ++n) {
            const int col = wc + n * 16 + lr;
            bfr[n] = *(const short8*)&Bs[col * BKT + ((g ^ ((col >> 1) & 3)) * 8)];
        }
#pragma unroll
        for (int m = 0; m < 4; ++m)
#pragma unroll
            for (int n = 0; n < 4; ++n)
                acc[m][n] = __builtin_amdgcn_mfma_f32_16x16x32_bf16(af[m], bfr[n], acc[m][n], 0, 0, 0);
    }

#pragma unroll
    for (int m = 0; m < 4; ++m) {
#pragma unroll
        for (int i = 0; i < 4; ++i) {
            const int row = bm + wr + m * 16 + g * 4 + i;
            if (row >= M) continue;
#pragma unroll
            for (int n = 0; n < 4; ++n) {
                const int col = bn + wc + n * 16 + lr;
                C[(size_t)row * ldc + col] = f2bf(acc[m][n][i]);
            }
        }
    }
}

// ---------------- fused gather-aggregate + combine, F=256, C bf16 [50000][512] ----------------
__global__ void k_gac256(const ushort* __restrict__ C, const int* __restrict__ rowptr,
                         const int* __restrict__ eidx, const float* __restrict__ bias,
                         ushort* __restrict__ hout) {
    int gid = blockIdx.x * blockDim.x + threadIdx.x;
    int node = gid >> 6;
    if (node >= NODES) return;
    const int l4 = (gid & 63) << 2;
    const int beg = rowptr[node];
    const int end = rowptr[node + 1];
    float a0 = 0.f, a1 = 0.f, a2 = 0.f, a3 = 0.f;
    for (int e = beg; e < end; ++e) {
        const int s = eidx[e];
        const ushort4 v = *(const ushort4*)&C[(size_t)s * 512 + 256 + l4];
        a0 += bf2f(v.x); a1 += bf2f(v.y); a2 += bf2f(v.z); a3 += bf2f(v.w);
    }
    const float inv = 1.f / (float)max(end - beg, 1);
    const ushort4 hs = *(const ushort4*)&C[(size_t)node * 512 + l4];
    const f32x4 b = *(const f32x4*)&bias[l4];
    float o0 = fmaxf(bf2f(hs.x) + a0 * inv + b[0], 0.f);
    float o1 = fmaxf(bf2f(hs.y) + a1 * inv + b[1], 0.f);
    float o2 = fmaxf(bf2f(hs.z) + a2 * inv + b[2], 0.f);
    float o3 = fmaxf(bf2f(hs.w) + a3 * inv + b[3], 0.f);
    ushort4 w;
    w.x = f2bf(o0); w.y = f2bf(o1); w.z = f2bf(o2); w.w = f2bf(o3);
    *(ushort4*)&hout[(size_t)node * 256 + l4] = w;
}

// ---------------- final layer gather, F=47, C2 bf16 [50000][128] ----------------
__global__ void k_gac47(const ushort* __restrict__ C, const int* __restrict__ rowptr,
                        const int* __restrict__ eidx, const float* __restrict__ bias,
                        float* __restrict__ out) {
    int gid = blockIdx.x * blockDim.x + threadIdx.x;
    int node = gid >> 6;
    if (node >= NODES) return;
    const int l = gid & 63;
    if (l >= FC) return;
    const int beg = rowptr[node];
    const int end = rowptr[node + 1];
    float acc = 0.f;
    for (int e = beg; e < end; ++e) {
        const int s = eidx[e];
        acc += bf2f(C[(size_t)s * 128 + 64 + l]);
    }
    const float inv = 1.f / (float)max(end - beg, 1);
    out[(size_t)node * FC + l] = bf2f(C[(size_t)node * 128 + l]) + acc * inv + bias[l];
}

extern "C" void kernel_launch(void* const* d_in, const int* in_sizes, int n_in,
                              void* d_out, int out_size, void* d_ws, size_t ws_size,
                              hipStream_t stream) {
    const float* x       = (const float*)d_in[0];
    const int*   src     = (const int*)d_in[1];
    const int*   dst     = (const int*)d_in[2];
    const float* Wself0  = (const float*)d_in[3];
    const float* Wneigh0 = (const float*)d_in[4];
    const float* b0      = (const float*)d_in[5];
    const float* Wself1  = (const float*)d_in[6];
    const float* Wneigh1 = (const float*)d_in[7];
    const float* b1      = (const float*)d_in[8];
    const float* Wself2  = (const float*)d_in[9];
    const float* Wneigh2 = (const float*)d_in[10];
    const float* b2      = (const float*)d_in[11];
    float* out = (float*)d_out;

    char* w = (char*)d_ws;
    ushort* Cbuf = (ushort*)w;                       w += (size_t)NODES * 512 * 2;  // 51.2 MB
    ushort* hbuf = (ushort*)w;                       w += (size_t)NODES * 256 * 2;  // 25.6 MB
    ushort* Wt0  = (ushort*)w;                       w += (size_t)512 * KP0 * 2;
    ushort* Wt1  = (ushort*)w;                       w += (size_t)512 * FH * 2;
    ushort* Wt2  = (ushort*)w;                       w += (size_t)128 * FH * 2;
    int* rowptr  = (int*)w;                          w += (NODES + 1) * sizeof(int);
    int* cursor  = (int*)w;                          w += NODES * sizeof(int);
    int* eidx    = (int*)w;

    dim3 blk(256);

    // ---- CSR build ----
    hipMemsetAsync(cursor, 0, NODES * sizeof(int), stream);
    k_deg_count<<<(EDGES + 255) / 256, blk, 0, stream>>>(dst, cursor, EDGES);
    k_scan<<<1, 1024, 0, stream>>>(cursor, rowptr, cursor, NODES);
    k_fill<<<(EDGES + 255) / 256, blk, 0, stream>>>(src, dst, cursor, eidx, EDGES);

    // ---- weight convert ----
    k_cvtw0<<<(512 * KP0 + 255) / 256, blk, 0, stream>>>(Wself0, Wneigh0, Wt0);
    k_cvtw1<<<(512 * FH + 255) / 256, blk, 0, stream>>>(Wself1, Wneigh1, Wt1);
    k_cvtw2<<<(128 * FH + 255) / 256, blk, 0, stream>>>(Wself2, Wneigh2, Wt2);

    const int gat_blocks = (int)(((size_t)NODES * 64 + 255) / 256);

    // ---- Layer 0: C0 = x @ [Wself0|Wneigh0]  (M=50000, N=512, K=988/992) ----
    k_mm<1><<<dim3(4, (NODES + BMT - 1) / BMT), blk, 0, stream>>>(
        x, Wt0, Cbuf, NODES, FIN, FIN, KP0, 512);
    k_gac256<<<gat_blocks, blk, 0, stream>>>(Cbuf, rowptr, eidx, b0, hbuf);

    // ---- Layer 1: C1 = h1 @ [Wself1|Wneigh1]  (K=256) ----
    k_mm<0><<<dim3(4, (NODES + BMT - 1) / BMT), blk, 0, stream>>>(
        hbuf, Wt1, Cbuf, NODES, FH, FH, FH, 512);
    k_gac256<<<gat_blocks, blk, 0, stream>>>(Cbuf, rowptr, eidx, b1, hbuf);

    // ---- Layer 2: C2 = h2 @ [Wself2|Wneigh2 padded]  (N=128, K=256) ----
    k_mm<0><<<dim3(1, (NODES + BMT - 1) / BMT), blk, 0, stream>>>(
        hbuf, Wt2, Cbuf, NODES, FH, FH, FH, 128);
    k_gac47<<<gat_blocks, blk, 0, stream>>>(Cbuf, rowptr, eidx, b2, out);
}

// Round 4
// 526.733 us; speedup vs baseline: 7.4618x; 1.0462x over previous
//
#include <hip/hip_runtime.h>
#include <hip/hip_bf16.h>
#include <cstdint>

#define NODES 50000
#define EDGES 400000
#define FIN   988
#define KP0   992      // FIN padded to multiple of 32
#define FH    256
#define FC    47

typedef __attribute__((ext_vector_type(8))) short short8;
typedef __attribute__((ext_vector_type(4))) float f32x4;

__device__ __forceinline__ ushort f2bf(float x) {      // RNE f32 -> bf16
    union { float f; uint32_t u; } v; v.f = x;
    uint32_t r = v.u + 0x7FFF + ((v.u >> 16) & 1);
    return (ushort)(r >> 16);
}
__device__ __forceinline__ float bf2f(ushort u) {
    union { uint32_t u; float f; } v; v.u = ((uint32_t)u) << 16;
    return v.f;
}

// ---------------- CSR build ----------------
__global__ void k_deg_count(const int* __restrict__ dst, int* __restrict__ deg, int nE) {
    int i = blockIdx.x * blockDim.x + threadIdx.x;
    if (i < nE) atomicAdd(&deg[dst[i]], 1);
}

__global__ __launch_bounds__(1024) void k_scan(const int* __restrict__ deg,
                                               int* __restrict__ rowptr,
                                               int* __restrict__ cursor, int n) {
    __shared__ int sums[1024];
    const int t = threadIdx.x;
    const int chunk = (n + 1023) / 1024;
    const int b = t * chunk;
    const int e = min(b + chunk, n);
    int s = 0;
    for (int i = b; i < e; ++i) s += deg[i];
    sums[t] = s;
    __syncthreads();
    for (int off = 1; off < 1024; off <<= 1) {
        int v = 0;
        if (t >= off) v = sums[t - off];
        __syncthreads();
        if (t >= off) sums[t] += v;
        __syncthreads();
    }
    int excl = (t == 0) ? 0 : sums[t - 1];
    for (int i = b; i < e; ++i) {
        int d = deg[i];
        rowptr[i] = excl;
        cursor[i] = excl;
        excl += d;
    }
    if (t == 1023) rowptr[n] = sums[1023];
}

__global__ void k_fill(const int* __restrict__ src, const int* __restrict__ dst,
                       int* __restrict__ cursor, int* __restrict__ eidx, int nE) {
    int i = blockIdx.x * blockDim.x + threadIdx.x;
    if (i < nE) {
        int d = dst[i];
        int p = atomicAdd(&cursor[d], 1);
        eidx[p] = src[i];
    }
}

// ---------------- weight transpose+convert ----------------
__global__ void k_cvtw0(const float* __restrict__ Ws, const float* __restrict__ Wn,
                        ushort* __restrict__ Wt) {
    int gid = blockIdx.x * blockDim.x + threadIdx.x;
    if (gid >= 512 * KP0) return;
    int n = gid / KP0, k = gid - n * KP0;
    float v = 0.f;
    if (k < FIN) v = (n < FH) ? Ws[(size_t)k * FH + n] : Wn[(size_t)k * FH + (n - FH)];
    Wt[gid] = f2bf(v);
}

__global__ void k_cvtw1(const float* __restrict__ Ws, const float* __restrict__ Wn,
                        ushort* __restrict__ Wt) {
    int gid = blockIdx.x * blockDim.x + threadIdx.x;
    if (gid >= 512 * FH) return;
    int n = gid >> 8, k = gid & 255;
    float v = (n < FH) ? Ws[(size_t)k * FH + n] : Wn[(size_t)k * FH + (n - FH)];
    Wt[gid] = f2bf(v);
}

__global__ void k_cvtw2(const float* __restrict__ Ws, const float* __restrict__ Wn,
                        ushort* __restrict__ Wt) {
    int gid = blockIdx.x * blockDim.x + threadIdx.x;
    if (gid >= 128 * FH) return;
    int n = gid >> 8, k = gid & 255;
    float v = 0.f;
    if (n < FC) v = Ws[(size_t)k * FC + n];
    else if (n >= 64 && n < 64 + FC) v = Wn[(size_t)k * FC + (n - 64)];
    Wt[gid] = f2bf(v);
}

// ---------------- bf16 MFMA GEMM ----------------
// C[M][ldc](bf16) = A[M][lda] @ Bt[N][Kpad]^T. 128x128 tile, BK=32, 4 waves,
// 4x4 16x16x32 fragments/wave. 1-D grid + bijective XCD-chunk swizzle so the
// nbx N-blocks of one M-row share an XCD L2 (A-panel re-reads become L2 hits).
// K-loop is software-pipelined: next tile's global loads issue before the
// current tile's frag-reads+MFMA, hiding load latency at ~3 waves/SIMD.
#define BMT 128
#define BKT 32

template<int AF32>
__device__ __forceinline__ void load_a(const void* Ap, int row, int M, int lda, int Ka,
                                       int kk, short8& a0, short8& a1) {
    if (AF32) {
        const float* A = (const float*)Ap;
        if (row < M) {
            const float* p = A + (size_t)row * lda + kk;
            if (kk + 15 < Ka) {
                f32x4 v0 = *(const f32x4*)(p);
                f32x4 v1 = *(const f32x4*)(p + 4);
                f32x4 v2 = *(const f32x4*)(p + 8);
                f32x4 v3 = *(const f32x4*)(p + 12);
#pragma unroll
                for (int i = 0; i < 4; ++i) {
                    a0[i] = (short)f2bf(v0[i]); a0[4 + i] = (short)f2bf(v1[i]);
                    a1[i] = (short)f2bf(v2[i]); a1[4 + i] = (short)f2bf(v3[i]);
                }
            } else {
#pragma unroll
                for (int i = 0; i < 8; ++i) {
                    float f0 = (kk + i < Ka) ? p[i] : 0.f;
                    float f1 = (kk + 8 + i < Ka) ? p[8 + i] : 0.f;
                    a0[i] = (short)f2bf(f0); a1[i] = (short)f2bf(f1);
                }
            }
        } else {
#pragma unroll
            for (int i = 0; i < 8; ++i) { a0[i] = 0; a1[i] = 0; }
        }
    } else {
        const ushort* A = (const ushort*)Ap;
        if (row < M) {
            const ushort* p = A + (size_t)row * lda + kk;
            a0 = *(const short8*)p;
            a1 = *(const short8*)(p + 8);
        } else {
#pragma unroll
            for (int i = 0; i < 8; ++i) { a0[i] = 0; a1[i] = 0; }
        }
    }
}

template<int AF32>
__global__ __launch_bounds__(256) void k_mm(const void* __restrict__ Ap,
                                            const ushort* __restrict__ Bt,
                                            ushort* __restrict__ C,
                                            const int M, const int lda,
                                            const int Ka, const int Kpad,
                                            const int ldc, const int nbx) {
    // bijective XCD-chunk swizzle (nwg % 8 != 0 safe)
    const int nwg = gridDim.x;
    const int bid = blockIdx.x;
    const int q = nwg >> 3, r = nwg & 7;
    const int xcd = bid & 7, ii = bid >> 3;
    const int swz = (xcd < r ? xcd * (q + 1) : r * (q + 1) + (xcd - r) * q) + ii;
    const int bm = (swz / nbx) * BMT;
    const int bn = (swz % nbx) * BMT;

    __shared__ ushort As[BMT * BKT];
    __shared__ ushort Bs[BMT * BKT];
    const int t = threadIdx.x;
    const int wid = t >> 6, lane = t & 63;
    const int wr = (wid >> 1) * 64, wc = (wid & 1) * 64;
    const int lr = lane & 15, g = lane >> 4;

    f32x4 acc[4][4] = {};

    const int sr = t >> 1;          // staging row 0..127
    const int kb = (t & 1) * 16;    // k-chunk offset within tile
    const int s0 = (t & 1) * 2;     // first 16B slot
    const int sw = (sr >> 1) & 3;   // swizzle key for this row
    const int arow = bm + sr;
    const int brow = bn + sr;

    short8 ua0, ua1, ub0, ub1;
    load_a<AF32>(Ap, arow, M, lda, Ka, kb, ua0, ua1);
    {
        const ushort* p = Bt + (size_t)brow * Kpad + kb;
        ub0 = *(const short8*)p; ub1 = *(const short8*)(p + 8);
    }

    for (int k0 = 0; k0 < Kpad; k0 += BKT) {
        __syncthreads();   // previous iter's frag reads done before overwrite
        *(short8*)&As[sr * BKT + ((s0 ^ sw) * 8)]       = ua0;
        *(short8*)&As[sr * BKT + (((s0 + 1) ^ sw) * 8)] = ua1;
        *(short8*)&Bs[sr * BKT + ((s0 ^ sw) * 8)]       = ub0;
        *(short8*)&Bs[sr * BKT + (((s0 + 1) ^ sw) * 8)] = ub1;
        __syncthreads();

        // prefetch next K-tile while this tile computes
        short8 na0, na1, nb0, nb1;
        const bool more = (k0 + BKT) < Kpad;
        if (more) {
            load_a<AF32>(Ap, arow, M, lda, Ka, k0 + BKT + kb, na0, na1);
            const ushort* p = Bt + (size_t)brow * Kpad + (k0 + BKT + kb);
            nb0 = *(const short8*)p; nb1 = *(const short8*)(p + 8);
        }

        short8 af[4], bfr[4];
#pragma unroll
        for (int m = 0; m < 4; ++m) {
            const int row = wr + m * 16 + lr;
            af[m] = *(const short8*)&As[row * BKT + ((g ^ ((row >> 1) & 3)) * 8)];
        }
#pragma unroll
        for (int n = 0; n < 4; ++n) {
            const int col = wc + n * 16 + lr;
            bfr[n] = *(const short8*)&Bs[col * BKT + ((g ^ ((col >> 1) & 3)) * 8)];
        }
#pragma unroll
        for (int m = 0; m < 4; ++m)
#pragma unroll
            for (int n = 0; n < 4; ++n)
                acc[m][n] = __builtin_amdgcn_mfma_f32_16x16x32_bf16(af[m], bfr[n], acc[m][n], 0, 0, 0);

        if (more) { ua0 = na0; ua1 = na1; ub0 = nb0; ub1 = nb1; }
    }

#pragma unroll
    for (int m = 0; m < 4; ++m) {
#pragma unroll
        for (int i = 0; i < 4; ++i) {
            const int row = bm + wr + m * 16 + g * 4 + i;
            if (row >= M) continue;
#pragma unroll
            for (int n = 0; n < 4; ++n) {
                const int col = bn + wc + n * 16 + lr;
                C[(size_t)row * ldc + col] = f2bf(acc[m][n][i]);
            }
        }
    }
}

// ---------------- fused gather-aggregate + combine, F=256, C bf16 [50000][512] ----------------
__global__ void k_gac256(const ushort* __restrict__ C, const int* __restrict__ rowptr,
                         const int* __restrict__ eidx, const float* __restrict__ bias,
                         ushort* __restrict__ hout) {
    int gid = blockIdx.x * blockDim.x + threadIdx.x;
    int node = gid >> 6;
    if (node >= NODES) return;
    const int l4 = (gid & 63) << 2;
    const int beg = rowptr[node];
    const int end = rowptr[node + 1];
    float a0 = 0.f, a1 = 0.f, a2 = 0.f, a3 = 0.f;
    for (int e = beg; e < end; ++e) {
        const int s = eidx[e];
        const ushort4 v = *(const ushort4*)&C[(size_t)s * 512 + 256 + l4];
        a0 += bf2f(v.x); a1 += bf2f(v.y); a2 += bf2f(v.z); a3 += bf2f(v.w);
    }
    const float inv = 1.f / (float)max(end - beg, 1);
    const ushort4 hs = *(const ushort4*)&C[(size_t)node * 512 + l4];
    const f32x4 b = *(const f32x4*)&bias[l4];
    float o0 = fmaxf(bf2f(hs.x) + a0 * inv + b[0], 0.f);
    float o1 = fmaxf(bf2f(hs.y) + a1 * inv + b[1], 0.f);
    float o2 = fmaxf(bf2f(hs.z) + a2 * inv + b[2], 0.f);
    float o3 = fmaxf(bf2f(hs.w) + a3 * inv + b[3], 0.f);
    ushort4 w;
    w.x = f2bf(o0); w.y = f2bf(o1); w.z = f2bf(o2); w.w = f2bf(o3);
    *(ushort4*)&hout[(size_t)node * 256 + l4] = w;
}

// ---------------- final layer gather, F=47, C2 bf16 [50000][128] ----------------
__global__ void k_gac47(const ushort* __restrict__ C, const int* __restrict__ rowptr,
                        const int* __restrict__ eidx, const float* __restrict__ bias,
                        float* __restrict__ out) {
    int gid = blockIdx.x * blockDim.x + threadIdx.x;
    int node = gid >> 6;
    if (node >= NODES) return;
    const int l = gid & 63;
    if (l >= FC) return;
    const int beg = rowptr[node];
    const int end = rowptr[node + 1];
    float acc = 0.f;
    for (int e = beg; e < end; ++e) {
        const int s = eidx[e];
        acc += bf2f(C[(size_t)s * 128 + 64 + l]);
    }
    const float inv = 1.f / (float)max(end - beg, 1);
    out[(size_t)node * FC + l] = bf2f(C[(size_t)node * 128 + l]) + acc * inv + bias[l];
}

extern "C" void kernel_launch(void* const* d_in, const int* in_sizes, int n_in,
                              void* d_out, int out_size, void* d_ws, size_t ws_size,
                              hipStream_t stream) {
    const float* x       = (const float*)d_in[0];
    const int*   src     = (const int*)d_in[1];
    const int*   dst     = (const int*)d_in[2];
    const float* Wself0  = (const float*)d_in[3];
    const float* Wneigh0 = (const float*)d_in[4];
    const float* b0      = (const float*)d_in[5];
    const float* Wself1  = (const float*)d_in[6];
    const float* Wneigh1 = (const float*)d_in[7];
    const float* b1      = (const float*)d_in[8];
    const float* Wself2  = (const float*)d_in[9];
    const float* Wneigh2 = (const float*)d_in[10];
    const float* b2      = (const float*)d_in[11];
    float* out = (float*)d_out;

    char* w = (char*)d_ws;
    ushort* Cbuf = (ushort*)w;                       w += (size_t)NODES * 512 * 2;  // 51.2 MB
    ushort* hbuf = (ushort*)w;                       w += (size_t)NODES * 256 * 2;  // 25.6 MB
    ushort* Wt0  = (ushort*)w;                       w += (size_t)512 * KP0 * 2;
    ushort* Wt1  = (ushort*)w;                       w += (size_t)512 * FH * 2;
    ushort* Wt2  = (ushort*)w;                       w += (size_t)128 * FH * 2;
    int* rowptr  = (int*)w;                          w += (NODES + 1) * sizeof(int);
    int* cursor  = (int*)w;                          w += NODES * sizeof(int);
    int* eidx    = (int*)w;

    dim3 blk(256);

    // ---- CSR build ----
    hipMemsetAsync(cursor, 0, NODES * sizeof(int), stream);
    k_deg_count<<<(EDGES + 255) / 256, blk, 0, stream>>>(dst, cursor, EDGES);
    k_scan<<<1, 1024, 0, stream>>>(cursor, rowptr, cursor, NODES);
    k_fill<<<(EDGES + 255) / 256, blk, 0, stream>>>(src, dst, cursor, eidx, EDGES);

    // ---- weight convert ----
    k_cvtw0<<<(512 * KP0 + 255) / 256, blk, 0, stream>>>(Wself0, Wneigh0, Wt0);
    k_cvtw1<<<(512 * FH + 255) / 256, blk, 0, stream>>>(Wself1, Wneigh1, Wt1);
    k_cvtw2<<<(128 * FH + 255) / 256, blk, 0, stream>>>(Wself2, Wneigh2, Wt2);

    const int gat_blocks = (int)(((size_t)NODES * 64 + 255) / 256);
    const int nbyM = (NODES + BMT - 1) / BMT;   // 391

    // ---- Layer 0: C0 = x @ [Wself0|Wneigh0]  (M=50000, N=512, K=988/992) ----
    k_mm<1><<<dim3(4 * nbyM), blk, 0, stream>>>(x, Wt0, Cbuf, NODES, FIN, FIN, KP0, 512, 4);
    k_gac256<<<gat_blocks, blk, 0, stream>>>(Cbuf, rowptr, eidx, b0, hbuf);

    // ---- Layer 1: C1 = h1 @ [Wself1|Wneigh1]  (K=256) ----
    k_mm<0><<<dim3(4 * nbyM), blk, 0, stream>>>(hbuf, Wt1, Cbuf, NODES, FH, FH, FH, 512, 4);
    k_gac256<<<gat_blocks, blk, 0, stream>>>(Cbuf, rowptr, eidx, b1, hbuf);

    // ---- Layer 2: C2 = h2 @ [Wself2|Wneigh2 padded]  (N=128, K=256) ----
    k_mm<0><<<dim3(nbyM), blk, 0, stream>>>(hbuf, Wt2, Cbuf, NODES, FH, FH, FH, 128, 1);
    k_gac47<<<gat_blocks, blk, 0, stream>>>(Cbuf, rowptr, eidx, b2, out);
}

// Round 5
// 512.132 us; speedup vs baseline: 7.6745x; 1.0285x over previous
//
#include <hip/hip_runtime.h>
#include <hip/hip_bf16.h>
#include <cstdint>

#define NODES 50000
#define EDGES 400000
#define FIN   988
#define KP0   992      // FIN padded to multiple of 32
#define FH    256
#define FC    47

typedef __attribute__((ext_vector_type(8))) short short8;
typedef __attribute__((ext_vector_type(4))) float f32x4;

__device__ __forceinline__ ushort f2bf(float x) {      // RNE f32 -> bf16
    union { float f; uint32_t u; } v; v.f = x;
    uint32_t r = v.u + 0x7FFF + ((v.u >> 16) & 1);
    return (ushort)(r >> 16);
}
__device__ __forceinline__ float bf2f(ushort u) {
    union { uint32_t u; float f; } v; v.u = ((uint32_t)u) << 16;
    return v.f;
}

// ---------------- CSR build ----------------
__global__ void k_deg_count(const int* __restrict__ dst, int* __restrict__ deg, int nE) {
    int i = blockIdx.x * blockDim.x + threadIdx.x;
    if (i < nE) atomicAdd(&deg[dst[i]], 1);
}

__global__ __launch_bounds__(1024) void k_scan(const int* __restrict__ deg,
                                               int* __restrict__ rowptr,
                                               int* __restrict__ cursor, int n) {
    __shared__ int sums[1024];
    const int t = threadIdx.x;
    const int chunk = (n + 1023) / 1024;
    const int b = t * chunk;
    const int e = min(b + chunk, n);
    int s = 0;
    for (int i = b; i < e; ++i) s += deg[i];
    sums[t] = s;
    __syncthreads();
    for (int off = 1; off < 1024; off <<= 1) {
        int v = 0;
        if (t >= off) v = sums[t - off];
        __syncthreads();
        if (t >= off) sums[t] += v;
        __syncthreads();
    }
    int excl = (t == 0) ? 0 : sums[t - 1];
    for (int i = b; i < e; ++i) {
        int d = deg[i];
        rowptr[i] = excl;
        cursor[i] = excl;
        excl += d;
    }
    if (t == 1023) rowptr[n] = sums[1023];
}

__global__ void k_fill(const int* __restrict__ src, const int* __restrict__ dst,
                       int* __restrict__ cursor, int* __restrict__ eidx, int nE) {
    int i = blockIdx.x * blockDim.x + threadIdx.x;
    if (i < nE) {
        int d = dst[i];
        int p = atomicAdd(&cursor[d], 1);
        eidx[p] = src[i];
    }
}

// ---------------- x (f32) -> xbf (bf16, K padded 988->992) ----------------
// one block per node row, 128 threads x 8 cols
__global__ __launch_bounds__(128) void k_cvtx(const float* __restrict__ x,
                                              ushort* __restrict__ xbf) {
    const int row = blockIdx.x;
    const int c8 = threadIdx.x * 8;
    if (c8 >= KP0) return;
    const float* p = x + (size_t)row * FIN + c8;
    short8 o;
    if (c8 + 8 <= FIN) {
        f32x4 v0 = *(const f32x4*)(p);
        f32x4 v1 = *(const f32x4*)(p + 4);
#pragma unroll
        for (int i = 0; i < 4; ++i) {
            o[i] = (short)f2bf(v0[i]);
            o[4 + i] = (short)f2bf(v1[i]);
        }
    } else {
#pragma unroll
        for (int i = 0; i < 8; ++i) {
            float f = (c8 + i < FIN) ? p[i] : 0.f;
            o[i] = (short)f2bf(f);
        }
    }
    *(short8*)&xbf[(size_t)row * KP0 + c8] = o;
}

// ---------------- weight transpose+convert ----------------
__global__ void k_cvtw0(const float* __restrict__ Ws, const float* __restrict__ Wn,
                        ushort* __restrict__ Wt) {
    int gid = blockIdx.x * blockDim.x + threadIdx.x;
    if (gid >= 512 * KP0) return;
    int n = gid / KP0, k = gid - n * KP0;
    float v = 0.f;
    if (k < FIN) v = (n < FH) ? Ws[(size_t)k * FH + n] : Wn[(size_t)k * FH + (n - FH)];
    Wt[gid] = f2bf(v);
}

__global__ void k_cvtw1(const float* __restrict__ Ws, const float* __restrict__ Wn,
                        ushort* __restrict__ Wt) {
    int gid = blockIdx.x * blockDim.x + threadIdx.x;
    if (gid >= 512 * FH) return;
    int n = gid >> 8, k = gid & 255;
    float v = (n < FH) ? Ws[(size_t)k * FH + n] : Wn[(size_t)k * FH + (n - FH)];
    Wt[gid] = f2bf(v);
}

__global__ void k_cvtw2(const float* __restrict__ Ws, const float* __restrict__ Wn,
                        ushort* __restrict__ Wt) {
    int gid = blockIdx.x * blockDim.x + threadIdx.x;
    if (gid >= 128 * FH) return;
    int n = gid >> 8, k = gid & 255;
    float v = 0.f;
    if (n < FC) v = Ws[(size_t)k * FC + n];
    else if (n >= 64 && n < 64 + FC) v = Wn[(size_t)k * FC + (n - 64)];
    Wt[gid] = f2bf(v);
}

// ---------------- bf16 MFMA GEMM ----------------
// C[M][ldc](bf16) = A[M][lda](bf16) @ Bt[N][Kpad]^T. 128x128 tile, BK=32,
// 4 waves, 4x4 16x16x32 frags/wave. LDS double-buffered with ONE raw
// s_barrier per K-step: global prefetch loads stay in flight ACROSS the
// barrier (no vmcnt drain) and resolve at next iteration's ds_write reg
// dependency -> load latency hides under a full K-step of LDS+MFMA.
// Race ledger: lgkmcnt(0) before each barrier drains (a) this iter's frag
// reads of buf[b] (buf[b] is overwritten right after the barrier by the
// next iter's write) and (b) this iter's writes to buf[b^1] (read by all
// waves right after the barrier). sched_barrier(0) pins ops at the barrier.
#define BMT 128
#define BKT 32

__global__ __launch_bounds__(256) void k_mm(const ushort* __restrict__ A,
                                            const ushort* __restrict__ Bt,
                                            ushort* __restrict__ C,
                                            const int M, const int lda,
                                            const int Kpad, const int ldc,
                                            const int nbx) {
    // bijective XCD-chunk swizzle (safe for nwg % 8 != 0)
    const int nwg = gridDim.x;
    const int bid = blockIdx.x;
    const int q = nwg >> 3, r = nwg & 7;
    const int xcd = bid & 7, ii = bid >> 3;
    const int swz = (xcd < r ? xcd * (q + 1) : r * (q + 1) + (xcd - r) * q) + ii;
    const int bm = (swz / nbx) * BMT;
    const int bn = (swz % nbx) * BMT;

    __shared__ ushort As[2][BMT * BKT];
    __shared__ ushort Bs[2][BMT * BKT];
    const int t = threadIdx.x;
    const int wid = t >> 6, lane = t & 63;
    const int wr = (wid >> 1) * 64, wc = (wid & 1) * 64;
    const int lr = lane & 15, g = lane >> 4;

    f32x4 acc[4][4] = {};

    const int sr = t >> 1;          // staging row 0..127
    const int kb = (t & 1) * 16;    // k offset within tile
    const int s0 = (t & 1) * 2;     // first 16B slot
    const int sw = (sr >> 1) & 3;   // conflict-free slot swizzle (measured 0 conflicts)
    const int arow = min(bm + sr, M - 1);   // clamp: garbage rows never stored
    const ushort* Aprow = A + (size_t)arow * lda + kb;
    const ushort* Bprow = Bt + (size_t)(bn + sr) * Kpad + kb;

    const int wo0 = sr * BKT + ((s0 ^ sw) * 8);
    const int wo1 = sr * BKT + (((s0 + 1) ^ sw) * 8);

    // prologue: tile 0 -> LDS buf 0; issue tile 1 loads
    short8 ua0 = *(const short8*)(Aprow);
    short8 ua1 = *(const short8*)(Aprow + 8);
    short8 ub0 = *(const short8*)(Bprow);
    short8 ub1 = *(const short8*)(Bprow + 8);
    *(short8*)&As[0][wo0] = ua0; *(short8*)&As[0][wo1] = ua1;
    *(short8*)&Bs[0][wo0] = ub0; *(short8*)&Bs[0][wo1] = ub1;
    if (BKT < Kpad) {
        ua0 = *(const short8*)(Aprow + BKT);
        ua1 = *(const short8*)(Aprow + BKT + 8);
        ub0 = *(const short8*)(Bprow + BKT);
        ub1 = *(const short8*)(Bprow + BKT + 8);
    }
    asm volatile("s_waitcnt lgkmcnt(0)" ::: "memory");
    __builtin_amdgcn_s_barrier();
    __builtin_amdgcn_sched_barrier(0);

    int b = 0;
    for (int k0 = 0; k0 < Kpad; k0 += BKT, b ^= 1) {
        const bool hn = (k0 + BKT) < Kpad;
        if (hn) {
            // write prefetched tile k+1 into buf[b^1] (compiler inserts the
            // vmcnt wait for the reg dependency here -> loads drain HERE,
            // not at the barrier)
            ushort* dA = &As[b ^ 1][0];
            ushort* dB = &Bs[b ^ 1][0];
            *(short8*)&dA[wo0] = ua0; *(short8*)&dA[wo1] = ua1;
            *(short8*)&dB[wo0] = ub0; *(short8*)&dB[wo1] = ub1;
            if (k0 + 2 * BKT < Kpad) {   // issue tile k+2 loads
                const int kk = k0 + 2 * BKT;
                ua0 = *(const short8*)(Aprow + kk);
                ua1 = *(const short8*)(Aprow + kk + 8);
                ub0 = *(const short8*)(Bprow + kk);
                ub1 = *(const short8*)(Bprow + kk + 8);
            }
        }
        short8 af[4], bfr[4];
#pragma unroll
        for (int m = 0; m < 4; ++m) {
            const int row = wr + m * 16 + lr;
            af[m] = *(const short8*)&As[b][row * BKT + ((g ^ ((row >> 1) & 3)) * 8)];
        }
#pragma unroll
        for (int n = 0; n < 4; ++n) {
            const int col = wc + n * 16 + lr;
            bfr[n] = *(const short8*)&Bs[b][col * BKT + ((g ^ ((col >> 1) & 3)) * 8)];
        }
#pragma unroll
        for (int m = 0; m < 4; ++m)
#pragma unroll
            for (int n = 0; n < 4; ++n)
                acc[m][n] = __builtin_amdgcn_mfma_f32_16x16x32_bf16(af[m], bfr[n], acc[m][n], 0, 0, 0);

        if (hn) {
            asm volatile("s_waitcnt lgkmcnt(0)" ::: "memory");
            __builtin_amdgcn_s_barrier();
            __builtin_amdgcn_sched_barrier(0);
        }
    }

#pragma unroll
    for (int m = 0; m < 4; ++m) {
#pragma unroll
        for (int i = 0; i < 4; ++i) {
            const int row = bm + wr + m * 16 + g * 4 + i;
            if (row >= M) continue;
#pragma unroll
            for (int n = 0; n < 4; ++n) {
                const int col = bn + wc + n * 16 + lr;
                C[(size_t)row * ldc + col] = f2bf(acc[m][n][i]);
            }
        }
    }
}

// ---------------- fused gather-aggregate + combine, F=256, C bf16 [50000][512] ----------------
__global__ void k_gac256(const ushort* __restrict__ C, const int* __restrict__ rowptr,
                         const int* __restrict__ eidx, const float* __restrict__ bias,
                         ushort* __restrict__ hout) {
    int gid = blockIdx.x * blockDim.x + threadIdx.x;
    int node = gid >> 6;
    if (node >= NODES) return;
    const int l4 = (gid & 63) << 2;
    const int beg = rowptr[node];
    const int end = rowptr[node + 1];
    float a0 = 0.f, a1 = 0.f, a2 = 0.f, a3 = 0.f;
    for (int e = beg; e < end; ++e) {
        const int s = eidx[e];
        const ushort4 v = *(const ushort4*)&C[(size_t)s * 512 + 256 + l4];
        a0 += bf2f(v.x); a1 += bf2f(v.y); a2 += bf2f(v.z); a3 += bf2f(v.w);
    }
    const float inv = 1.f / (float)max(end - beg, 1);
    const ushort4 hs = *(const ushort4*)&C[(size_t)node * 512 + l4];
    const f32x4 b = *(const f32x4*)&bias[l4];
    float o0 = fmaxf(bf2f(hs.x) + a0 * inv + b[0], 0.f);
    float o1 = fmaxf(bf2f(hs.y) + a1 * inv + b[1], 0.f);
    float o2 = fmaxf(bf2f(hs.z) + a2 * inv + b[2], 0.f);
    float o3 = fmaxf(bf2f(hs.w) + a3 * inv + b[3], 0.f);
    ushort4 w;
    w.x = f2bf(o0); w.y = f2bf(o1); w.z = f2bf(o2); w.w = f2bf(o3);
    *(ushort4*)&hout[(size_t)node * 256 + l4] = w;
}

// ---------------- final layer gather, F=47, C2 bf16 [50000][128] ----------------
__global__ void k_gac47(const ushort* __restrict__ C, const int* __restrict__ rowptr,
                        const int* __restrict__ eidx, const float* __restrict__ bias,
                        float* __restrict__ out) {
    int gid = blockIdx.x * blockDim.x + threadIdx.x;
    int node = gid >> 6;
    if (node >= NODES) return;
    const int l = gid & 63;
    if (l >= FC) return;
    const int beg = rowptr[node];
    const int end = rowptr[node + 1];
    float acc = 0.f;
    for (int e = beg; e < end; ++e) {
        const int s = eidx[e];
        acc += bf2f(C[(size_t)s * 128 + 64 + l]);
    }
    const float inv = 1.f / (float)max(end - beg, 1);
    out[(size_t)node * FC + l] = bf2f(C[(size_t)node * 128 + l]) + acc * inv + bias[l];
}

extern "C" void kernel_launch(void* const* d_in, const int* in_sizes, int n_in,
                              void* d_out, int out_size, void* d_ws, size_t ws_size,
                              hipStream_t stream) {
    const float* x       = (const float*)d_in[0];
    const int*   src     = (const int*)d_in[1];
    const int*   dst     = (const int*)d_in[2];
    const float* Wself0  = (const float*)d_in[3];
    const float* Wneigh0 = (const float*)d_in[4];
    const float* b0      = (const float*)d_in[5];
    const float* Wself1  = (const float*)d_in[6];
    const float* Wneigh1 = (const float*)d_in[7];
    const float* b1      = (const float*)d_in[8];
    const float* Wself2  = (const float*)d_in[9];
    const float* Wneigh2 = (const float*)d_in[10];
    const float* b2      = (const float*)d_in[11];
    float* out = (float*)d_out;

    char* w = (char*)d_ws;
    ushort* Cbuf = (ushort*)w;   w += (size_t)NODES * 512 * 2;   // 51.2 MB
    ushort* xbf  = (ushort*)w;   w += (size_t)NODES * KP0 * 2;   // 99.2 MB
    ushort* hbuf = xbf;          // aliases xbf: xbf dead once L0 GEMM completes
    ushort* Wt0  = (ushort*)w;   w += (size_t)512 * KP0 * 2;
    ushort* Wt1  = (ushort*)w;   w += (size_t)512 * FH * 2;
    ushort* Wt2  = (ushort*)w;   w += (size_t)128 * FH * 2;
    int* rowptr  = (int*)w;      w += (NODES + 1) * sizeof(int);
    int* cursor  = (int*)w;      w += NODES * sizeof(int);
    int* eidx    = (int*)w;

    dim3 blk(256);

    // ---- CSR build ----
    hipMemsetAsync(cursor, 0, NODES * sizeof(int), stream);
    k_deg_count<<<(EDGES + 255) / 256, blk, 0, stream>>>(dst, cursor, EDGES);
    k_scan<<<1, 1024, 0, stream>>>(cursor, rowptr, cursor, NODES);
    k_fill<<<(EDGES + 255) / 256, blk, 0, stream>>>(src, dst, cursor, eidx, EDGES);

    // ---- conversions ----
    k_cvtw0<<<(512 * KP0 + 255) / 256, blk, 0, stream>>>(Wself0, Wneigh0, Wt0);
    k_cvtw1<<<(512 * FH + 255) / 256, blk, 0, stream>>>(Wself1, Wneigh1, Wt1);
    k_cvtw2<<<(128 * FH + 255) / 256, blk, 0, stream>>>(Wself2, Wneigh2, Wt2);
    k_cvtx<<<NODES, 128, 0, stream>>>(x, xbf);

    const int gat_blocks = (int)(((size_t)NODES * 64 + 255) / 256);
    const int nbyM = (NODES + BMT - 1) / BMT;   // 391

    // ---- Layer 0: C0 = xbf @ [Wself0|Wneigh0]  (M=50000, N=512, K=992) ----
    k_mm<<<dim3(4 * nbyM), blk, 0, stream>>>(xbf, Wt0, Cbuf, NODES, KP0, KP0, 512, 4);
    k_gac256<<<gat_blocks, blk, 0, stream>>>(Cbuf, rowptr, eidx, b0, hbuf);

    // ---- Layer 1: C1 = h1 @ [Wself1|Wneigh1]  (K=256) ----
    k_mm<<<dim3(4 * nbyM), blk, 0, stream>>>(hbuf, Wt1, Cbuf, NODES, FH, FH, 512, 4);
    k_gac256<<<gat_blocks, blk, 0, stream>>>(Cbuf, rowptr, eidx, b1, hbuf);

    // ---- Layer 2: C2 = h2 @ [Wself2|Wneigh2 padded]  (N=128, K=256) ----
    k_mm<<<dim3(nbyM), blk, 0, stream>>>(hbuf, Wt2, Cbuf, NODES, FH, FH, 128, 1);
    k_gac47<<<gat_blocks, blk, 0, stream>>>(Cbuf, rowptr, eidx, b2, out);
}

// Round 6
// 446.720 us; speedup vs baseline: 8.7983x; 1.1464x over previous
//
#include <hip/hip_runtime.h>
#include <hip/hip_bf16.h>
#include <cstdint>

#define NODES 50000
#define EDGES 400000
#define FIN   988
#define KP0   992      // FIN padded to multiple of 32
#define FH    256
#define FC    47

typedef __attribute__((ext_vector_type(8))) short short8;
typedef __attribute__((ext_vector_type(4))) float f32x4;

__device__ __forceinline__ ushort f2bf(float x) {      // RNE f32 -> bf16
    union { float f; uint32_t u; } v; v.f = x;
    uint32_t r = v.u + 0x7FFF + ((v.u >> 16) & 1);
    return (ushort)(r >> 16);
}
__device__ __forceinline__ float bf2f(ushort u) {
    union { uint32_t u; float f; } v; v.u = ((uint32_t)u) << 16;
    return v.f;
}

// ---------------- CSR build ----------------
__global__ void k_deg_count(const int* __restrict__ dst, int* __restrict__ deg, int nE) {
    int i = blockIdx.x * blockDim.x + threadIdx.x;
    if (i < nE) atomicAdd(&deg[dst[i]], 1);
}

__global__ __launch_bounds__(1024) void k_scan(const int* __restrict__ deg,
                                               int* __restrict__ rowptr,
                                               int* __restrict__ cursor, int n) {
    __shared__ int sums[1024];
    const int t = threadIdx.x;
    const int chunk = (n + 1023) / 1024;
    const int b = t * chunk;
    const int e = min(b + chunk, n);
    int s = 0;
    for (int i = b; i < e; ++i) s += deg[i];
    sums[t] = s;
    __syncthreads();
    for (int off = 1; off < 1024; off <<= 1) {
        int v = 0;
        if (t >= off) v = sums[t - off];
        __syncthreads();
        if (t >= off) sums[t] += v;
        __syncthreads();
    }
    int excl = (t == 0) ? 0 : sums[t - 1];
    for (int i = b; i < e; ++i) {
        int d = deg[i];
        rowptr[i] = excl;
        cursor[i] = excl;
        excl += d;
    }
    if (t == 1023) rowptr[n] = sums[1023];
}

__global__ void k_fill(const int* __restrict__ src, const int* __restrict__ dst,
                       int* __restrict__ cursor, int* __restrict__ eidx, int nE) {
    int i = blockIdx.x * blockDim.x + threadIdx.x;
    if (i < nE) {
        int d = dst[i];
        int p = atomicAdd(&cursor[d], 1);
        eidx[p] = src[i];
    }
}

// ---------------- merged weight transpose+convert (3 layers, 1 kernel) ----------------
#define W0E (512 * KP0)
#define W1E (512 * FH)
#define W2E (128 * FH)
__global__ void k_cvtw(const float* __restrict__ Ws0, const float* __restrict__ Wn0,
                       const float* __restrict__ Ws1, const float* __restrict__ Wn1,
                       const float* __restrict__ Ws2, const float* __restrict__ Wn2,
                       ushort* __restrict__ Wt0, ushort* __restrict__ Wt1,
                       ushort* __restrict__ Wt2) {
    int gid = blockIdx.x * blockDim.x + threadIdx.x;
    if (gid < W0E) {
        int n = gid / KP0, k = gid - n * KP0;
        float v = 0.f;
        if (k < FIN) v = (n < FH) ? Ws0[(size_t)k * FH + n] : Wn0[(size_t)k * FH + (n - FH)];
        Wt0[gid] = f2bf(v);
    } else if (gid < W0E + W1E) {
        int g = gid - W0E;
        int n = g >> 8, k = g & 255;
        float v = (n < FH) ? Ws1[(size_t)k * FH + n] : Wn1[(size_t)k * FH + (n - FH)];
        Wt1[g] = f2bf(v);
    } else if (gid < W0E + W1E + W2E) {
        int g = gid - W0E - W1E;
        int n = g >> 8, k = g & 255;
        float v = 0.f;
        if (n < FC) v = Ws2[(size_t)k * FC + n];
        else if (n >= 64 && n < 64 + FC) v = Wn2[(size_t)k * FC + (n - 64)];
        Wt2[g] = f2bf(v);
    }
}

// ---------------- bf16 MFMA GEMM ----------------
// C[M][ldc](bf16) = A[M][lda] @ Bt[N][Kpad]^T. 128x128 tile, BK=32, 4 waves,
// 4x4 16x16x32 frags/wave. LDS double-buffered, ONE raw s_barrier per K-step:
// global prefetch loads stay in flight ACROSS the barrier (lgkmcnt(0) only)
// and drain at next iteration's ds_write reg dependency.
// AF32=1: A is f32, converted to bf16 at ds_write time (prefetch regs stay
// f32 so the vmcnt drain still happens at the write, keeping the window).
// LDS frag-read offsets precomputed outside the loop (VALUBusy was 45%).
#define BMT 128
#define BKT 32
#define BUFE (BMT * BKT)

template<int AF32>
__global__ __launch_bounds__(256) void k_mm(const void* __restrict__ Ap,
                                            const ushort* __restrict__ Bt,
                                            ushort* __restrict__ C,
                                            const int M, const int lda, const int Ka,
                                            const int Kpad, const int ldc,
                                            const int nbx) {
    // bijective XCD-chunk swizzle (safe for nwg % 8 != 0)
    const int nwg = gridDim.x;
    const int bid = blockIdx.x;
    const int q = nwg >> 3, r = nwg & 7;
    const int xcd = bid & 7, ii = bid >> 3;
    const int swz = (xcd < r ? xcd * (q + 1) : r * (q + 1) + (xcd - r) * q) + ii;
    const int bm = (swz / nbx) * BMT;
    const int bn = (swz % nbx) * BMT;

    __shared__ ushort As[2 * BUFE];
    __shared__ ushort Bs[2 * BUFE];
    const int t = threadIdx.x;
    const int wid = t >> 6, lane = t & 63;
    const int wr = (wid >> 1) * 64, wc = (wid & 1) * 64;
    const int lr = lane & 15, g = lane >> 4;

    f32x4 acc[4][4] = {};

    const int sr = t >> 1;          // staging row 0..127
    const int kb = (t & 1) * 16;    // k offset within tile
    const int s0 = (t & 1) * 2;     // first 16B slot
    const int sw = (sr >> 1) & 3;   // conflict-free slot swizzle (measured: 0 conflicts)
    const int arow = min(bm + sr, M - 1);
    const float*  Af  = AF32 ? (const float*)Ap + (size_t)arow * lda + kb : nullptr;
    const ushort* Abf = AF32 ? nullptr : (const ushort*)Ap + (size_t)arow * lda + kb;
    const ushort* Bp  = Bt + (size_t)(bn + sr) * Kpad + kb;

    const int wo0 = sr * BKT + ((s0 ^ sw) * 8);
    const int wo1 = sr * BKT + (((s0 + 1) ^ sw) * 8);

    // precomputed frag-read element offsets (loop adds b*BUFE only)
    int roA[4], roB[4];
#pragma unroll
    for (int m = 0; m < 4; ++m) {
        const int row = wr + m * 16 + lr;
        roA[m] = row * BKT + ((g ^ ((row >> 1) & 3)) * 8);
    }
#pragma unroll
    for (int n = 0; n < 4; ++n) {
        const int col = wc + n * 16 + lr;
        roB[n] = col * BKT + ((g ^ ((col >> 1) & 3)) * 8);
    }

    // prefetch registers
    f32x4 va[4];            // AF32 path (f32 until ds_write)
    short8 ua0, ua1;        // bf16 path
    short8 ub0, ub1;

    auto loadA = [&](int kk) {
        if constexpr (AF32) {
            const float* p = Af + kk;
            if (kk + 16 <= Ka) {
                va[0] = *(const f32x4*)(p);
                va[1] = *(const f32x4*)(p + 4);
                va[2] = *(const f32x4*)(p + 8);
                va[3] = *(const f32x4*)(p + 12);
            } else {
#pragma unroll
                for (int j = 0; j < 4; ++j)
#pragma unroll
                    for (int i = 0; i < 4; ++i)
                        va[j][i] = (kk + j * 4 + i < Ka) ? p[j * 4 + i] : 0.f;
            }
        } else {
            const ushort* p = Abf + kk;
            ua0 = *(const short8*)p;
            ua1 = *(const short8*)(p + 8);
        }
    };
    auto loadB = [&](int kk) {
        ub0 = *(const short8*)(Bp + kk);
        ub1 = *(const short8*)(Bp + kk + 8);
    };
    auto writeAB = [&](int bsel) {
        ushort* dA = &As[bsel * BUFE];
        ushort* dB = &Bs[bsel * BUFE];
        if constexpr (AF32) {
            short8 t0, t1;
#pragma unroll
            for (int i = 0; i < 4; ++i) {
                t0[i] = (short)f2bf(va[0][i]); t0[4 + i] = (short)f2bf(va[1][i]);
                t1[i] = (short)f2bf(va[2][i]); t1[4 + i] = (short)f2bf(va[3][i]);
            }
            *(short8*)&dA[wo0] = t0; *(short8*)&dA[wo1] = t1;
        } else {
            *(short8*)&dA[wo0] = ua0; *(short8*)&dA[wo1] = ua1;
        }
        *(short8*)&dB[wo0] = ub0; *(short8*)&dB[wo1] = ub1;
    };

    // prologue: tile 0 -> buf 0; issue tile 1 loads
    loadA(0); loadB(0);
    writeAB(0);
    if (BKT < Kpad) { loadA(BKT); loadB(BKT); }
    asm volatile("s_waitcnt lgkmcnt(0)" ::: "memory");
    __builtin_amdgcn_s_barrier();
    __builtin_amdgcn_sched_barrier(0);

    int b = 0;
    for (int k0 = 0; k0 < Kpad; k0 += BKT, b ^= 1) {
        const bool hn = (k0 + BKT) < Kpad;
        if (hn) {
            writeAB(b ^ 1);   // vmcnt drain happens here, not at the barrier
            if (k0 + 2 * BKT < Kpad) { loadA(k0 + 2 * BKT); loadB(k0 + 2 * BKT); }
        }
        const int bo = b * BUFE;
        short8 af[4], bfr[4];
#pragma unroll
        for (int m = 0; m < 4; ++m) af[m] = *(const short8*)&As[bo + roA[m]];
#pragma unroll
        for (int n = 0; n < 4; ++n) bfr[n] = *(const short8*)&Bs[bo + roB[n]];
#pragma unroll
        for (int m = 0; m < 4; ++m)
#pragma unroll
            for (int n = 0; n < 4; ++n)
                acc[m][n] = __builtin_amdgcn_mfma_f32_16x16x32_bf16(af[m], bfr[n], acc[m][n], 0, 0, 0);

        if (hn) {
            asm volatile("s_waitcnt lgkmcnt(0)" ::: "memory");
            __builtin_amdgcn_s_barrier();
            __builtin_amdgcn_sched_barrier(0);
        }
    }

#pragma unroll
    for (int m = 0; m < 4; ++m) {
#pragma unroll
        for (int i = 0; i < 4; ++i) {
            const int row = bm + wr + m * 16 + g * 4 + i;
            if (row >= M) continue;
#pragma unroll
            for (int n = 0; n < 4; ++n) {
                const int col = bn + wc + n * 16 + lr;
                C[(size_t)row * ldc + col] = f2bf(acc[m][n][i]);
            }
        }
    }
}

// ---------------- fused gather-aggregate + combine, F=256, C bf16 [50000][512] ----------------
__global__ void k_gac256(const ushort* __restrict__ C, const int* __restrict__ rowptr,
                         const int* __restrict__ eidx, const float* __restrict__ bias,
                         ushort* __restrict__ hout) {
    int gid = blockIdx.x * blockDim.x + threadIdx.x;
    int node = gid >> 6;
    if (node >= NODES) return;
    const int l4 = (gid & 63) << 2;
    const int beg = rowptr[node];
    const int end = rowptr[node + 1];
    float a0 = 0.f, a1 = 0.f, a2 = 0.f, a3 = 0.f;
    int e = beg;
    for (; e + 1 < end; e += 2) {           // unroll-2: two loads in flight
        const int s0 = eidx[e], s1 = eidx[e + 1];
        const ushort4 v0 = *(const ushort4*)&C[(size_t)s0 * 512 + 256 + l4];
        const ushort4 v1 = *(const ushort4*)&C[(size_t)s1 * 512 + 256 + l4];
        a0 += bf2f(v0.x) + bf2f(v1.x);
        a1 += bf2f(v0.y) + bf2f(v1.y);
        a2 += bf2f(v0.z) + bf2f(v1.z);
        a3 += bf2f(v0.w) + bf2f(v1.w);
    }
    if (e < end) {
        const int s = eidx[e];
        const ushort4 v = *(const ushort4*)&C[(size_t)s * 512 + 256 + l4];
        a0 += bf2f(v.x); a1 += bf2f(v.y); a2 += bf2f(v.z); a3 += bf2f(v.w);
    }
    const float inv = 1.f / (float)max(end - beg, 1);
    const ushort4 hs = *(const ushort4*)&C[(size_t)node * 512 + l4];
    const f32x4 bv = *(const f32x4*)&bias[l4];
    ushort4 w;
    w.x = f2bf(fmaxf(bf2f(hs.x) + a0 * inv + bv[0], 0.f));
    w.y = f2bf(fmaxf(bf2f(hs.y) + a1 * inv + bv[1], 0.f));
    w.z = f2bf(fmaxf(bf2f(hs.z) + a2 * inv + bv[2], 0.f));
    w.w = f2bf(fmaxf(bf2f(hs.w) + a3 * inv + bv[3], 0.f));
    *(ushort4*)&hout[(size_t)node * 256 + l4] = w;
}

// ---------------- final layer gather, F=47, C2 bf16 [50000][128] ----------------
__global__ void k_gac47(const ushort* __restrict__ C, const int* __restrict__ rowptr,
                        const int* __restrict__ eidx, const float* __restrict__ bias,
                        float* __restrict__ out) {
    int gid = blockIdx.x * blockDim.x + threadIdx.x;
    int node = gid >> 6;
    if (node >= NODES) return;
    const int l = gid & 63;
    if (l >= FC) return;
    const int beg = rowptr[node];
    const int end = rowptr[node + 1];
    float acc = 0.f;
    int e = beg;
    for (; e + 1 < end; e += 2) {
        const int s0 = eidx[e], s1 = eidx[e + 1];
        acc += bf2f(C[(size_t)s0 * 128 + 64 + l]) + bf2f(C[(size_t)s1 * 128 + 64 + l]);
    }
    if (e < end) acc += bf2f(C[(size_t)eidx[e] * 128 + 64 + l]);
    const float inv = 1.f / (float)max(end - beg, 1);
    out[(size_t)node * FC + l] = bf2f(C[(size_t)node * 128 + l]) + acc * inv + bias[l];
}

extern "C" void kernel_launch(void* const* d_in, const int* in_sizes, int n_in,
                              void* d_out, int out_size, void* d_ws, size_t ws_size,
                              hipStream_t stream) {
    const float* x       = (const float*)d_in[0];
    const int*   src     = (const int*)d_in[1];
    const int*   dst     = (const int*)d_in[2];
    const float* Wself0  = (const float*)d_in[3];
    const float* Wneigh0 = (const float*)d_in[4];
    const float* b0      = (const float*)d_in[5];
    const float* Wself1  = (const float*)d_in[6];
    const float* Wneigh1 = (const float*)d_in[7];
    const float* b1      = (const float*)d_in[8];
    const float* Wself2  = (const float*)d_in[9];
    const float* Wneigh2 = (const float*)d_in[10];
    const float* b2      = (const float*)d_in[11];
    float* out = (float*)d_out;

    char* w = (char*)d_ws;
    ushort* Cbuf = (ushort*)w;   w += (size_t)NODES * 512 * 2;   // 51.2 MB
    ushort* hbuf = (ushort*)w;   w += (size_t)NODES * FH * 2;    // 25.6 MB
    ushort* Wt0  = (ushort*)w;   w += (size_t)W0E * 2;
    ushort* Wt1  = (ushort*)w;   w += (size_t)W1E * 2;
    ushort* Wt2  = (ushort*)w;   w += (size_t)W2E * 2;
    int* rowptr  = (int*)w;      w += (NODES + 1) * sizeof(int);
    int* cursor  = (int*)w;      w += NODES * sizeof(int);
    int* eidx    = (int*)w;

    dim3 blk(256);

    // ---- CSR build ----
    hipMemsetAsync(cursor, 0, NODES * sizeof(int), stream);
    k_deg_count<<<(EDGES + 255) / 256, blk, 0, stream>>>(dst, cursor, EDGES);
    k_scan<<<1, 1024, 0, stream>>>(cursor, rowptr, cursor, NODES);
    k_fill<<<(EDGES + 255) / 256, blk, 0, stream>>>(src, dst, cursor, eidx, EDGES);

    // ---- weight convert (single kernel) ----
    k_cvtw<<<(W0E + W1E + W2E + 255) / 256, blk, 0, stream>>>(
        Wself0, Wneigh0, Wself1, Wneigh1, Wself2, Wneigh2, Wt0, Wt1, Wt2);

    const int gat_blocks = (int)(((size_t)NODES * 64 + 255) / 256);
    const int nbyM = (NODES + BMT - 1) / BMT;   // 391

    // ---- Layer 0: C0 = x @ [Wself0|Wneigh0]  (f32 A converted in-flight) ----
    k_mm<1><<<dim3(4 * nbyM), blk, 0, stream>>>(x, Wt0, Cbuf, NODES, FIN, FIN, KP0, 512, 4);
    k_gac256<<<gat_blocks, blk, 0, stream>>>(Cbuf, rowptr, eidx, b0, hbuf);

    // ---- Layer 1: C1 = h1 @ [Wself1|Wneigh1]  (K=256) ----
    k_mm<0><<<dim3(4 * nbyM), blk, 0, stream>>>(hbuf, Wt1, Cbuf, NODES, FH, FH, FH, 512, 4);
    k_gac256<<<gat_blocks, blk, 0, stream>>>(Cbuf, rowptr, eidx, b1, hbuf);

    // ---- Layer 2: C2 = h2 @ [Wself2|Wneigh2 padded]  (N=128, K=256) ----
    k_mm<0><<<dim3(nbyM), blk, 0, stream>>>(hbuf, Wt2, Cbuf, NODES, FH, FH, FH, 128, 1);
    k_gac47<<<gat_blocks, blk, 0, stream>>>(Cbuf, rowptr, eidx, b2, out);
}

// Round 7
// 437.530 us; speedup vs baseline: 8.9831x; 1.0210x over previous
//
#include <hip/hip_runtime.h>
#include <hip/hip_bf16.h>
#include <cstdint>

#define NODES 50000
#define EDGES 400000
#define FIN   988
#define KP0   992      // FIN padded to multiple of 32
#define FH    256
#define FC    47

typedef __attribute__((ext_vector_type(8))) short short8;
typedef __attribute__((ext_vector_type(4))) float f32x4;

__device__ __forceinline__ ushort f2bf(float x) {      // RNE f32 -> bf16
    union { float f; uint32_t u; } v; v.f = x;
    uint32_t r = v.u + 0x7FFF + ((v.u >> 16) & 1);
    return (ushort)(r >> 16);
}
__device__ __forceinline__ float bf2f(ushort u) {
    union { uint32_t u; float f; } v; v.u = ((uint32_t)u) << 16;
    return v.f;
}
__device__ __forceinline__ uint32_t cvtpk_bf(float lo, float hi) {  // RNE pack, 1 VALU op
    uint32_t r;
    asm("v_cvt_pk_bf16_f32 %0, %1, %2" : "=v"(r) : "v"(lo), "v"(hi));
    return r;
}
__device__ __forceinline__ void g2l16(const void* g, void* l) {
    __builtin_amdgcn_global_load_lds((const __attribute__((address_space(1))) void*)g,
                                     (__attribute__((address_space(3))) void*)l, 16, 0, 0);
}

// ---------------- CSR build ----------------
__global__ void k_deg_count(const int* __restrict__ dst, int* __restrict__ deg, int nE) {
    int i = blockIdx.x * blockDim.x + threadIdx.x;
    if (i < nE) atomicAdd(&deg[dst[i]], 1);
}

__global__ __launch_bounds__(1024) void k_scan(const int* __restrict__ deg,
                                               int* __restrict__ rowptr,
                                               int* __restrict__ cursor, int n) {
    __shared__ int sums[1024];
    const int t = threadIdx.x;
    const int chunk = (n + 1023) / 1024;
    const int b = t * chunk;
    const int e = min(b + chunk, n);
    int s = 0;
    for (int i = b; i < e; ++i) s += deg[i];
    sums[t] = s;
    __syncthreads();
    for (int off = 1; off < 1024; off <<= 1) {
        int v = 0;
        if (t >= off) v = sums[t - off];
        __syncthreads();
        if (t >= off) sums[t] += v;
        __syncthreads();
    }
    int excl = (t == 0) ? 0 : sums[t - 1];
    for (int i = b; i < e; ++i) {
        int d = deg[i];
        rowptr[i] = excl;
        cursor[i] = excl;
        excl += d;
    }
    if (t == 1023) rowptr[n] = sums[1023];
}

__global__ void k_fill(const int* __restrict__ src, const int* __restrict__ dst,
                       int* __restrict__ cursor, int* __restrict__ eidx, int nE) {
    int i = blockIdx.x * blockDim.x + threadIdx.x;
    if (i < nE) {
        int d = dst[i];
        int p = atomicAdd(&cursor[d], 1);
        eidx[p] = src[i];
    }
}

// ---------------- merged weight transpose+convert, PRE-SWIZZLED ----------------
// Stored layout: within each 64B (32-bf16) K-tile chunk of row n, the four
// 16B slots are permuted slot_stored = slot_logical ^ (n&3). The GEMM stages
// Wt linearly via global_load_lds and applies the XOR at frag-read time.
#define W0E (512 * KP0)
#define W1E (512 * FH)
#define W2E (128 * FH)
__global__ void k_cvtw(const float* __restrict__ Ws0, const float* __restrict__ Wn0,
                       const float* __restrict__ Ws1, const float* __restrict__ Wn1,
                       const float* __restrict__ Ws2, const float* __restrict__ Wn2,
                       ushort* __restrict__ Wt0, ushort* __restrict__ Wt1,
                       ushort* __restrict__ Wt2) {
    int gid = blockIdx.x * blockDim.x + threadIdx.x;
    if (gid < W0E) {
        int n = gid / KP0, ks = gid - n * KP0;
        int kl = (ks & ~31) + ((((ks >> 3) & 3) ^ (n & 3)) << 3) + (ks & 7);
        float v = 0.f;
        if (kl < FIN) v = (n < FH) ? Ws0[(size_t)kl * FH + n] : Wn0[(size_t)kl * FH + (n - FH)];
        Wt0[gid] = f2bf(v);
    } else if (gid < W0E + W1E) {
        int g = gid - W0E;
        int n = g >> 8, ks = g & 255;
        int kl = (ks & ~31) + ((((ks >> 3) & 3) ^ (n & 3)) << 3) + (ks & 7);
        float v = (n < FH) ? Ws1[(size_t)kl * FH + n] : Wn1[(size_t)kl * FH + (n - FH)];
        Wt1[g] = f2bf(v);
    } else if (gid < W0E + W1E + W2E) {
        int g = gid - W0E - W1E;
        int n = g >> 8, ks = g & 255;
        int kl = (ks & ~31) + ((((ks >> 3) & 3) ^ (n & 3)) << 3) + (ks & 7);
        float v = 0.f;
        if (n < FC) v = Ws2[(size_t)kl * FC + n];
        else if (n >= 64 && n < 64 + FC) v = Wn2[(size_t)kl * FC + (n - 64)];
        Wt2[g] = f2bf(v);
    }
}

// ---------------- bf16 MFMA GEMM, m97 structure ----------------
// C[M][ldc](bf16) = A[M][lda] @ Bt[N][Kpad]^T. 128x128 tile, BK=32, 4 waves,
// 4x4 16x16x32 frags/wave. Staging ENTIRELY via global_load_lds (no staging
// registers -> low VGPR -> 4+ blocks/CU; cross-block TLP hides the per-block
// vmcnt(0) drain at __syncthreads, m97/m114 mechanism).
// LDS is linear (gload_lds constraint); conflict-free reads come from
// source-side swizzle: Wt pre-swizzled (k_cvtw), hbuf pre-swizzled (k_gac256),
// L0's f32 A fetched with inverse-swizzled per-lane global addresses.
// AF32=1: A staged as raw f32, converted at frag-read via v_cvt_pk_bf16_f32.
#define BMT 128
#define BKT 32

template<int AF32>
__global__ __launch_bounds__(256, 4) void k_mm(const void* __restrict__ Ap,
                                               const ushort* __restrict__ Bt,
                                               ushort* __restrict__ C,
                                               const int M, const int lda,
                                               const int Kpad, const int ldc,
                                               const int nbx) {
    // bijective XCD-chunk swizzle (safe for nwg % 8 != 0)
    const int nwg = gridDim.x;
    const int bid = blockIdx.x;
    const int q = nwg >> 3, r = nwg & 7;
    const int xcd = bid & 7, ii = bid >> 3;
    const int swz = (xcd < r ? xcd * (q + 1) : r * (q + 1) + (xcd - r) * q) + ii;
    const int bm = (swz / nbx) * BMT;
    const int bn = (swz % nbx) * BMT;

    __shared__ ushort As[(AF32 ? 2 : 1) * BMT * BKT];   // f32 A needs 2x bytes
    __shared__ ushort Bs[BMT * BKT];
    const float* Asf = (const float*)As;

    const int t = threadIdx.x;
    const int wid = t >> 6, lane = t & 63;
    const int wr = (wid >> 1) * 64, wc = (wid & 1) * 64;
    const int lr = lane & 15, g = lane >> 4;

    f32x4 acc[4][4] = {};

    // ---- staging descriptors ----
    // B tile: 128 rows x 32 bf16 = 8KB = 2 issues x 4 waves x 1KB.
    const ushort* bsrc[2]; ushort* bdst[2];
#pragma unroll
    for (int j = 0; j < 2; ++j) {
        const int c = j * 4 + wid;                 // 1KB chunk 0..7
        const int row = c * 16 + (lane >> 2);      // 64B rows
        bsrc[j] = Bt + (size_t)(bn + row) * Kpad + ((lane & 3) << 3);
        bdst[j] = &Bs[c * 512];
    }
    const float*  asrcf[4]; ushort* adstf[4];
    const ushort* asrcb[2]; ushort* adstb[2];
    const float* aend = nullptr;
    if (AF32) {
        const float* A = (const float*)Ap;
        aend = A + ((size_t)M * lda - 4);          // clamp: last 16B of A
#pragma unroll
        for (int j = 0; j < 4; ++j) {              // 16KB = 4 issues
            const int c = j * 4 + wid;             // chunk 0..15
            const int row = c * 8 + (lane >> 3);   // 128B rows
            const int arow = min(bm + row, M - 1);
            const int scol = ((lane & 7) ^ (row & 7)) << 2;  // inverse swizzle
            asrcf[j] = A + (size_t)arow * lda + scol;
            adstf[j] = &As[c * 512];
        }
    } else {
        const ushort* A = (const ushort*)Ap;
#pragma unroll
        for (int j = 0; j < 2; ++j) {
            const int c = j * 4 + wid;
            const int row = c * 16 + (lane >> 2);
            const int arow = min(bm + row, M - 1);
            asrcb[j] = A + (size_t)arow * lda + ((lane & 3) << 3);  // hbuf pre-swizzled
            adstb[j] = &As[c * 512];
        }
    }

    // ---- frag-read offsets (swizzle-matched, hoisted) ----
    int roB[4], roA0[4], roA1[4];
#pragma unroll
    for (int n = 0; n < 4; ++n) {
        const int col = wc + n * 16 + lr;
        roB[n] = col * 32 + ((g ^ (col & 3)) << 3);
    }
#pragma unroll
    for (int m = 0; m < 4; ++m) {
        const int row = wr + m * 16 + lr;
        if (AF32) {   // f32 elem offsets, two 16B slots per frag
            roA0[m] = row * 32 + (((2 * g) ^ (row & 7)) << 2);
            roA1[m] = row * 32 + (((2 * g + 1) ^ (row & 7)) << 2);
        } else {
            roA0[m] = row * 32 + ((g ^ (row & 3)) << 3);
            roA1[m] = 0;
        }
    }

    for (int k0 = 0; k0 < Kpad; k0 += BKT) {
        if (AF32) {
#pragma unroll
            for (int j = 0; j < 4; ++j) {
                const float* p = asrcf[j] + k0;
                p = (p > aend) ? aend : p;   // OOB-16B clamp (K-pad cols x zero weights)
                g2l16(p, adstf[j]);
            }
        } else {
#pragma unroll
            for (int j = 0; j < 2; ++j) g2l16(asrcb[j] + k0, adstb[j]);
        }
#pragma unroll
        for (int j = 0; j < 2; ++j) g2l16(bsrc[j] + k0, bdst[j]);
        __syncthreads();   // vmcnt(0) drain: tile resident

        short8 af[4], bfr[4];
        if (AF32) {
#pragma unroll
            for (int m = 0; m < 4; ++m) {
                const f32x4 lo = *(const f32x4*)&Asf[roA0[m]];
                const f32x4 hi = *(const f32x4*)&Asf[roA1[m]];
                union { uint32_t u[4]; short8 s; } pk;
                pk.u[0] = cvtpk_bf(lo[0], lo[1]);
                pk.u[1] = cvtpk_bf(lo[2], lo[3]);
                pk.u[2] = cvtpk_bf(hi[0], hi[1]);
                pk.u[3] = cvtpk_bf(hi[2], hi[3]);
                af[m] = pk.s;
            }
        } else {
#pragma unroll
            for (int m = 0; m < 4; ++m) af[m] = *(const short8*)&As[roA0[m]];
        }
#pragma unroll
        for (int n = 0; n < 4; ++n) bfr[n] = *(const short8*)&Bs[roB[n]];
#pragma unroll
        for (int m = 0; m < 4; ++m)
#pragma unroll
            for (int n = 0; n < 4; ++n)
                acc[m][n] = __builtin_amdgcn_mfma_f32_16x16x32_bf16(af[m], bfr[n], acc[m][n], 0, 0, 0);

        __syncthreads();   // all frag reads done before next tile overwrites
    }

#pragma unroll
    for (int m = 0; m < 4; ++m) {
#pragma unroll
        for (int i = 0; i < 4; ++i) {
            const int row = bm + wr + m * 16 + g * 4 + i;
            if (row >= M) continue;
#pragma unroll
            for (int n = 0; n < 4; ++n) {
                const int col = bn + wc + n * 16 + lr;
                C[(size_t)row * ldc + col] = f2bf(acc[m][n][i]);
            }
        }
    }
}

// ---------------- fused gather-aggregate + combine, F=256 ----------------
// Output hbuf is written PRE-SWIZZLED (slot^(node&3) within each 64B chunk)
// so the next layer's GEMM can stage it linearly via global_load_lds.
__global__ void k_gac256(const ushort* __restrict__ C, const int* __restrict__ rowptr,
                         const int* __restrict__ eidx, const float* __restrict__ bias,
                         ushort* __restrict__ hout) {
    int gid = blockIdx.x * blockDim.x + threadIdx.x;
    int node = gid >> 6;
    if (node >= NODES) return;
    const int l4 = (gid & 63) << 2;
    const int beg = rowptr[node];
    const int end = rowptr[node + 1];
    float a0 = 0.f, a1 = 0.f, a2 = 0.f, a3 = 0.f;
    int e = beg;
    for (; e + 1 < end; e += 2) {
        const int s0 = eidx[e], s1 = eidx[e + 1];
        const ushort4 v0 = *(const ushort4*)&C[(size_t)s0 * 512 + 256 + l4];
        const ushort4 v1 = *(const ushort4*)&C[(size_t)s1 * 512 + 256 + l4];
        a0 += bf2f(v0.x) + bf2f(v1.x);
        a1 += bf2f(v0.y) + bf2f(v1.y);
        a2 += bf2f(v0.z) + bf2f(v1.z);
        a3 += bf2f(v0.w) + bf2f(v1.w);
    }
    if (e < end) {
        const int s = eidx[e];
        const ushort4 v = *(const ushort4*)&C[(size_t)s * 512 + 256 + l4];
        a0 += bf2f(v.x); a1 += bf2f(v.y); a2 += bf2f(v.z); a3 += bf2f(v.w);
    }
    const float inv = 1.f / (float)max(end - beg, 1);
    const ushort4 hs = *(const ushort4*)&C[(size_t)node * 512 + l4];
    const f32x4 bv = *(const f32x4*)&bias[l4];
    ushort4 w;
    w.x = f2bf(fmaxf(bf2f(hs.x) + a0 * inv + bv[0], 0.f));
    w.y = f2bf(fmaxf(bf2f(hs.y) + a1 * inv + bv[1], 0.f));
    w.z = f2bf(fmaxf(bf2f(hs.z) + a2 * inv + bv[2], 0.f));
    w.w = f2bf(fmaxf(bf2f(hs.w) + a3 * inv + bv[3], 0.f));
    // baked swizzle: logical slot sl -> stored slot sl^(node&3), within 32-elem tile
    const int scol = (l4 & ~31) + ((((l4 >> 3) & 3) ^ (node & 3)) << 3) + (l4 & 7);
    *(ushort4*)&hout[(size_t)node * 256 + scol] = w;
}

// ---------------- final layer gather, F=47, C2 bf16 [50000][128] ----------------
__global__ void k_gac47(const ushort* __restrict__ C, const int* __restrict__ rowptr,
                        const int* __restrict__ eidx, const float* __restrict__ bias,
                        float* __restrict__ out) {
    int gid = blockIdx.x * blockDim.x + threadIdx.x;
    int node = gid >> 6;
    if (node >= NODES) return;
    const int l = gid & 63;
    if (l >= FC) return;
    const int beg = rowptr[node];
    const int end = rowptr[node + 1];
    float acc = 0.f;
    int e = beg;
    for (; e + 1 < end; e += 2) {
        const int s0 = eidx[e], s1 = eidx[e + 1];
        acc += bf2f(C[(size_t)s0 * 128 + 64 + l]) + bf2f(C[(size_t)s1 * 128 + 64 + l]);
    }
    if (e < end) acc += bf2f(C[(size_t)eidx[e] * 128 + 64 + l]);
    const float inv = 1.f / (float)max(end - beg, 1);
    out[(size_t)node * FC + l] = bf2f(C[(size_t)node * 128 + l]) + acc * inv + bias[l];
}

extern "C" void kernel_launch(void* const* d_in, const int* in_sizes, int n_in,
                              void* d_out, int out_size, void* d_ws, size_t ws_size,
                              hipStream_t stream) {
    const float* x       = (const float*)d_in[0];
    const int*   src     = (const int*)d_in[1];
    const int*   dst     = (const int*)d_in[2];
    const float* Wself0  = (const float*)d_in[3];
    const float* Wneigh0 = (const float*)d_in[4];
    const float* b0      = (const float*)d_in[5];
    const float* Wself1  = (const float*)d_in[6];
    const float* Wneigh1 = (const float*)d_in[7];
    const float* b1      = (const float*)d_in[8];
    const float* Wself2  = (const float*)d_in[9];
    const float* Wneigh2 = (const float*)d_in[10];
    const float* b2      = (const float*)d_in[11];
    float* out = (float*)d_out;

    char* w = (char*)d_ws;
    ushort* Cbuf = (ushort*)w;   w += (size_t)NODES * 512 * 2;   // 51.2 MB
    ushort* hbuf = (ushort*)w;   w += (size_t)NODES * FH * 2;    // 25.6 MB
    ushort* Wt0  = (ushort*)w;   w += (size_t)W0E * 2;
    ushort* Wt1  = (ushort*)w;   w += (size_t)W1E * 2;
    ushort* Wt2  = (ushort*)w;   w += (size_t)W2E * 2;
    int* rowptr  = (int*)w;      w += (NODES + 1) * sizeof(int);
    int* cursor  = (int*)w;      w += NODES * sizeof(int);
    int* eidx    = (int*)w;

    dim3 blk(256);

    // ---- CSR build ----
    hipMemsetAsync(cursor, 0, NODES * sizeof(int), stream);
    k_deg_count<<<(EDGES + 255) / 256, blk, 0, stream>>>(dst, cursor, EDGES);
    k_scan<<<1, 1024, 0, stream>>>(cursor, rowptr, cursor, NODES);
    k_fill<<<(EDGES + 255) / 256, blk, 0, stream>>>(src, dst, cursor, eidx, EDGES);

    // ---- weight convert (pre-swizzled) ----
    k_cvtw<<<(W0E + W1E + W2E + 255) / 256, blk, 0, stream>>>(
        Wself0, Wneigh0, Wself1, Wneigh1, Wself2, Wneigh2, Wt0, Wt1, Wt2);

    const int gat_blocks = (int)(((size_t)NODES * 64 + 255) / 256);
    const int nbyM = (NODES + BMT - 1) / BMT;   // 391

    // ---- Layer 0: C0 = x @ [Wself0|Wneigh0]  (f32 A staged raw, cvt at read) ----
    k_mm<1><<<dim3(4 * nbyM), blk, 0, stream>>>(x, Wt0, Cbuf, NODES, FIN, KP0, 512, 4);
    k_gac256<<<gat_blocks, blk, 0, stream>>>(Cbuf, rowptr, eidx, b0, hbuf);

    // ---- Layer 1: C1 = h1 @ [Wself1|Wneigh1]  (K=256) ----
    k_mm<0><<<dim3(4 * nbyM), blk, 0, stream>>>(hbuf, Wt1, Cbuf, NODES, FH, FH, 512, 4);
    k_gac256<<<gat_blocks, blk, 0, stream>>>(Cbuf, rowptr, eidx, b1, hbuf);

    // ---- Layer 2: C2 = h2 @ [Wself2|Wneigh2 padded]  (N=128, K=256) ----
    k_mm<0><<<dim3(nbyM), blk, 0, stream>>>(hbuf, Wt2, Cbuf, NODES, FH, FH, 128, 1);
    k_gac47<<<gat_blocks, blk, 0, stream>>>(Cbuf, rowptr, eidx, b2, out);
}